// Round 10
// baseline (631.693 us; speedup 1.0000x reference)
//
#include <hip/hip_runtime.h>
#include <hip/hip_fp16.h>

#define N_NODES   50000
#define N_EDGES   800000
#define NUM_GRAPHS 256
#define IN_FEAT   64
#define REL_DIM   32
#define HID       128
#define NUM_RELS  32
#define NUM_BASES 8
#define NUM_LAYERS 2

#define SCAN_BLKS ((N_NODES + 255) / 256)   // 196

typedef __attribute__((ext_vector_type(8))) short bf16x8;
typedef __attribute__((ext_vector_type(4))) float f32x4;

// async 16B global -> LDS (wave-uniform LDS base + lane*16; per-lane global src)
__device__ __forceinline__ void gld_lds16(void* lds, const void* g) {
    __builtin_amdgcn_global_load_lds(
        (const __attribute__((address_space(1))) unsigned int*)g,
        (__attribute__((address_space(3))) unsigned int*)lds, 16, 0, 0);
}

// ---------------- zero (float4 granularity) ----------------
__global__ void k_zero(float* __restrict__ p, int n4) {
    int i = blockIdx.x * 256 + threadIdx.x;
    if (i < n4) ((float4*)p)[i] = make_float4(0.f, 0.f, 0.f, 0.f);
}

// ---------------- CSR build: histogram, 3-phase scan, scatter ----------------
__global__ void k_hist(const int* __restrict__ dst, int* __restrict__ deg) {
    int e = blockIdx.x * 256 + threadIdx.x;
    if (e < N_EDGES) atomicAdd(&deg[dst[e]], 1);
}

__global__ void __launch_bounds__(256) k_scan_a(
    const int* __restrict__ deg, int* __restrict__ row_start, int* __restrict__ bsum) {
    __shared__ int s[256];
    int t = threadIdx.x;
    int idx = blockIdx.x * 256 + t;
    int v = (idx < N_NODES) ? deg[idx] : 0;
    s[t] = v;
    __syncthreads();
    for (int off = 1; off < 256; off <<= 1) {
        int u = (t >= off) ? s[t - off] : 0;
        __syncthreads();
        s[t] += u;
        __syncthreads();
    }
    if (idx < N_NODES) row_start[idx] = s[t] - v;   // local exclusive
    if (t == 255) bsum[blockIdx.x] = s[255];
}

__global__ void __launch_bounds__(256) k_scan_b(int* __restrict__ bsum,
                                                int* __restrict__ boff) {
    __shared__ int s[256];
    int t = threadIdx.x;
    int v = (t < SCAN_BLKS) ? bsum[t] : 0;
    s[t] = v;
    __syncthreads();
    for (int off = 1; off < 256; off <<= 1) {
        int u = (t >= off) ? s[t - off] : 0;
        __syncthreads();
        s[t] += u;
        __syncthreads();
    }
    if (t < SCAN_BLKS) boff[t] = s[t] - v;          // exclusive
}

__global__ void __launch_bounds__(256) k_scan_c(
    int* __restrict__ row_start, const int* __restrict__ boff,
    int* __restrict__ cursor) {
    int idx = blockIdx.x * 256 + threadIdx.x;
    if (idx < N_NODES) {
        int r = row_start[idx] + boff[blockIdx.x];
        row_start[idx] = r;
        cursor[idx] = r;
    }
    if (idx == 0) row_start[N_NODES] = N_EDGES;
}

// packed payload: (src << 5) | ety   (src < 2^17, ety < 32)
__global__ void k_scatter(const int* __restrict__ src, const int* __restrict__ dst,
                          const int* __restrict__ ety, int* __restrict__ cursor,
                          int* __restrict__ edge_p) {
    int e = blockIdx.x * 256 + threadIdx.x;
    if (e >= N_EDGES) return;
    int d = dst[e];
    int pos = atomicAdd(&cursor[d], 1);
    edge_p[pos] = (src[e] << 5) | ety[e];
}

// ---------------- input projection (16 nodes/block): h = relu([feat, er] @ W_in + b_in) ----------------
__global__ void __launch_bounds__(128) k_input(
    const float* __restrict__ feat, const int* __restrict__ qrel,
    const float* __restrict__ rel_emb, const float* __restrict__ Wi,
    const float* __restrict__ bi, float* __restrict__ h,
    unsigned short* __restrict__ h16, float* __restrict__ er) {
    int n0 = blockIdx.x * 16;
    int j = threadIdx.x;
    int u = j >> 3, q = j & 7;
    __shared__ float xT[96][16];
    {
        const float4* f4 = (const float4*)(feat + (size_t)(n0 + u) * IN_FEAT);
        float4 a = f4[q], b = f4[q + 8];
        xT[4 * q + 0][u] = a.x; xT[4 * q + 1][u] = a.y;
        xT[4 * q + 2][u] = a.z; xT[4 * q + 3][u] = a.w;
        xT[32 + 4 * q + 0][u] = b.x; xT[32 + 4 * q + 1][u] = b.y;
        xT[32 + 4 * q + 2][u] = b.z; xT[32 + 4 * q + 3][u] = b.w;
        int qr = qrel[n0 + u];
        float4 e4 = ((const float4*)(rel_emb + (size_t)qr * REL_DIM))[q];
        xT[64 + 4 * q + 0][u] = e4.x; xT[64 + 4 * q + 1][u] = e4.y;
        xT[64 + 4 * q + 2][u] = e4.z; xT[64 + 4 * q + 3][u] = e4.w;
        ((float4*)(er + (size_t)(n0 + u) * REL_DIM))[q] = e4;
    }
    __syncthreads();
    float bj = bi[j];
    float acc[16];
#pragma unroll
    for (int k = 0; k < 16; k++) acc[k] = bj;
    for (int d = 0; d < 96; d++) {
        float w = Wi[d * HID + j];
        float4 x0 = *(const float4*)&xT[d][0];
        float4 x1 = *(const float4*)&xT[d][4];
        float4 x2 = *(const float4*)&xT[d][8];
        float4 x3 = *(const float4*)&xT[d][12];
        acc[0]  = fmaf(x0.x, w, acc[0]);  acc[1]  = fmaf(x0.y, w, acc[1]);
        acc[2]  = fmaf(x0.z, w, acc[2]);  acc[3]  = fmaf(x0.w, w, acc[3]);
        acc[4]  = fmaf(x1.x, w, acc[4]);  acc[5]  = fmaf(x1.y, w, acc[5]);
        acc[6]  = fmaf(x1.z, w, acc[6]);  acc[7]  = fmaf(x1.w, w, acc[7]);
        acc[8]  = fmaf(x2.x, w, acc[8]);  acc[9]  = fmaf(x2.y, w, acc[9]);
        acc[10] = fmaf(x2.z, w, acc[10]); acc[11] = fmaf(x2.w, w, acc[11]);
        acc[12] = fmaf(x3.x, w, acc[12]); acc[13] = fmaf(x3.y, w, acc[13]);
        acc[14] = fmaf(x3.z, w, acc[14]); acc[15] = fmaf(x3.w, w, acc[15]);
    }
#pragma unroll
    for (int k = 0; k < 16; k++) {
        float v = fmaxf(acc[k], 0.f);
        h[(size_t)(n0 + k) * HID + j] = v;
        __half hv = __float2half(v);
        h16[(size_t)(n0 + k) * HID + j] = __builtin_bit_cast(unsigned short, hv);
    }
}

// RNE f32 -> (hi bf16, lo bf16)
__device__ inline void rne_split(float f, unsigned short& hi, unsigned short& lo) {
    unsigned u = __builtin_bit_cast(unsigned, f);
    unsigned rh = (u + 0x7fffu + ((u >> 16) & 1u)) & 0xffff0000u;
    hi = (unsigned short)(rh >> 16);
    float fl = f - __builtin_bit_cast(float, rh);
    unsigned ul = __builtin_bit_cast(unsigned, fl);
    lo = (unsigned short)((ul + 0x7fffu + ((ul >> 16) & 1u)) >> 16);
}

// ---------------- per-dst basis-weighted gather (fp16 h), split-bf16 output ----------------
// Ghi/Glo[n-c0][b*128+d] = bf16-split of sum_e c[ety,b]*h16[src,d]
__global__ void __launch_bounds__(256) k_mix2(
    const unsigned short* __restrict__ h16, const float* __restrict__ comp_l,
    const int* __restrict__ row_start, const int* __restrict__ edge_p,
    unsigned short* __restrict__ Ghi, unsigned short* __restrict__ Glo,
    int c0, int nc) {
    __shared__ float cs[NUM_RELS * NUM_BASES];
    if (threadIdx.x < NUM_RELS * NUM_BASES) cs[threadIdx.x] = comp_l[threadIdx.x];
    __syncthreads();
    int wave = threadIdx.x >> 6, lane = threadIdx.x & 63;
    int n = c0 + blockIdx.x * 4 + wave;
    if (n >= c0 + nc) return;
    int e0 = row_start[n], e1 = row_start[n + 1];
    float2 acc[NUM_BASES];
#pragma unroll
    for (int b = 0; b < NUM_BASES; b++) acc[b] = make_float2(0.f, 0.f);
    for (int e = e0; e < e1; e++) {
        int se = edge_p[e];
        const float* c = &cs[(se & 31) * NUM_BASES];
        unsigned u = ((const unsigned*)(h16 + (size_t)(se >> 5) * HID))[lane];
        __half2 hh = __builtin_bit_cast(__half2, u);
        float2 v = __half22float2(hh);
#pragma unroll
        for (int b = 0; b < NUM_BASES; b++) {
            acc[b].x = fmaf(c[b], v.x, acc[b].x);
            acc[b].y = fmaf(c[b], v.y, acc[b].y);
        }
    }
    size_t base = (size_t)(n - c0) * 1024 + 2 * lane;
#pragma unroll
    for (int b = 0; b < NUM_BASES; b++) {
        unsigned short hx, lx, hy, ly;
        rne_split(acc[b].x, hx, lx);
        rne_split(acc[b].y, hy, ly);
        *(ushort2*)&Ghi[base + b * 128] = make_ushort2(hx, hy);
        *(ushort2*)&Glo[base + b * 128] = make_ushort2(lx, ly);
    }
}

// ---------------- B fragment table: hi/lo bf16 of [Vl ; Wl] in MFMA fragment order ----------------
// entry (l, s, t, lane): 16 ushort = hi[8], lo[8];
// element j: B[k = s*32 + (lane>>4)*8 + j][col = t*16 + (lane&15)] of layer l.
__global__ void k_bfrag(const float* __restrict__ V, const float* __restrict__ W_loop,
                        unsigned short* __restrict__ Bf) {
    int idx = blockIdx.x * 256 + threadIdx.x;
    if (idx >= NUM_LAYERS * 36 * 8 * 64) return;
    int lane = idx & 63;
    int t = (idx >> 6) & 7;
    int s = (idx >> 9) % 36;
    int l = (idx >> 9) / 36;
    int col = t * 16 + (lane & 15);
    int kbase = s * 32 + (lane >> 4) * 8;
    unsigned short* o = Bf + (size_t)idx * 16;
#pragma unroll
    for (int j = 0; j < 8; j++) {
        int k = kbase + j;
        float f = (k < 1024) ? V[((size_t)l * 1024 + k) * HID + col]
                             : W_loop[((size_t)l * HID + (k - 1024)) * HID + col];
        unsigned short hi, lo;
        rne_split(f, hi, lo);
        o[j] = hi;
        o[8 + j] = lo;
    }
}

__device__ inline void split8(float4 a0, float4 a1, bf16x8& hi, bf16x8& lo) {
    float f[8] = {a0.x, a0.y, a0.z, a0.w, a1.x, a1.y, a1.z, a1.w};
#pragma unroll
    for (int j = 0; j < 8; j++) {
        unsigned short h, l;
        rne_split(f[j], h, l);
        hi[j] = (short)h;
        lo[j] = (short)l;
    }
}

// ---------------- MFMA GEMM (BM=64), global_load_lds double-buffered A staging ----------------
// out = relu([G | h] @ [Vl ; Wl] + bl); also writes fp16 copy.  M=nc, K=1152, N=128.
// Block = 64 rows x 128 cols, 4 waves col-split (wave w -> t=2w,2w+1), 4 row-groups.
// A-tile (BK=32, hi+lo) in LDS in fragment order: frag f = rowgroup*2 + (hi/lo), 1KB each.
__global__ void __launch_bounds__(256) k_gemm6(
    const unsigned short* __restrict__ Ghi, const unsigned short* __restrict__ Glo,
    const float* __restrict__ h, const unsigned short* __restrict__ Bf,
    const float* __restrict__ bl, float* __restrict__ out,
    unsigned short* __restrict__ out16, int c0, int nc) {
    __shared__ unsigned short smem[2][8][512];  // [buf][frag][1KB] = 16KB
    int lane = threadIdx.x & 63;
    int w = threadIdx.x >> 6;
    int rit = lane & 15, kg = lane >> 4;
    int r0 = blockIdx.x * 64;
    // wave w stages the hi/lo frag pair of row-group w
    int st_row = r0 + w * 16 + rit; if (st_row >= nc) st_row = nc - 1;
    const unsigned short* gsh = Ghi + (size_t)st_row * 1024 + kg * 8;
    const unsigned short* gsl = Glo + (size_t)st_row * 1024 + kg * 8;
    const bf16x8* bb = (const bf16x8*)Bf + ((size_t)(2 * w) * 64 + lane) * 2;
    f32x4 acc[4][2] = {};

#define MM(AH, AL, BH, BL, ACC) {                                        \
        ACC = __builtin_amdgcn_mfma_f32_16x16x32_bf16(AH, BH, ACC, 0, 0, 0); \
        ACC = __builtin_amdgcn_mfma_f32_16x16x32_bf16(AL, BH, ACC, 0, 0, 0); \
        ACC = __builtin_amdgcn_mfma_f32_16x16x32_bf16(AH, BL, ACC, 0, 0, 0); }
#define STAGE(BUF, STEP) {                                        \
        gld_lds16(&smem[BUF][2 * w + 0][0], gsh + (STEP) * 32);   \
        gld_lds16(&smem[BUF][2 * w + 1][0], gsl + (STEP) * 32); }
#define CSTEP(BUF, STEP) {                                                  \
        const bf16x8* bp = bb + (size_t)(STEP) * 1024;                      \
        bf16x8 bh0 = bp[0], bq0 = bp[1], bh1 = bp[128], bq1 = bp[129];      \
        _Pragma("unroll")                                                   \
        for (int i = 0; i < 4; i++) {                                       \
            bf16x8 ah = *(const bf16x8*)&smem[BUF][i * 2 + 0][lane * 8];    \
            bf16x8 al = *(const bf16x8*)&smem[BUF][i * 2 + 1][lane * 8];    \
            MM(ah, al, bh0, bq0, acc[i][0]);                                \
            MM(ah, al, bh1, bq1, acc[i][1]);                                \
        } }

    STAGE(0, 0);
    for (int t = 0; t < 32; t++) {
        __syncthreads();
        if (t < 31) STAGE((t + 1) & 1, t + 1);
        CSTEP(t & 1, t);
    }
    // K tail 1024..1151 (self-loop) from f32 h, split on the fly
    {
        const float* hp[4];
#pragma unroll
        for (int i = 0; i < 4; i++) {
            int rr = r0 + i * 16 + rit; if (rr >= nc) rr = nc - 1;
            hp[i] = h + (size_t)(c0 + rr) * HID + kg * 8;
        }
#pragma unroll
        for (int s = 32; s < 36; s++) {
            const bf16x8* bp = bb + (size_t)s * 1024;
            bf16x8 bh0 = bp[0], bq0 = bp[1], bh1 = bp[128], bq1 = bp[129];
            int o = (s - 32) * 32;
#pragma unroll
            for (int i = 0; i < 4; i++) {
                bf16x8 ah, al;
                split8(*(const float4*)(hp[i] + o), *(const float4*)(hp[i] + o + 4), ah, al);
                MM(ah, al, bh0, bq0, acc[i][0]);
                MM(ah, al, bh1, bq1, acc[i][1]);
            }
        }
    }
#undef MM
#undef STAGE
#undef CSTEP
#pragma unroll
    for (int i = 0; i < 4; i++) {
#pragma unroll
        for (int c = 0; c < 2; c++) {
            int col = (2 * w + c) * 16 + rit;
            float bc = bl[col];
#pragma unroll
            for (int q = 0; q < 4; q++) {
                int row = r0 + i * 16 + kg * 4 + q;
                if (row < nc) {
                    float v = fmaxf(acc[i][c][q] + bc, 0.f);
                    out[(size_t)(c0 + row) * HID + col] = v;
                    __half hv = __float2half(v);
                    out16[(size_t)(c0 + row) * HID + col] =
                        __builtin_bit_cast(unsigned short, hv);
                }
            }
        }
    }
}

// ---------------- attention scalar score per node (16 nodes/block) ----------------
__global__ void __launch_bounds__(128) k_score(
    const float* __restrict__ h, const float* __restrict__ er,
    const float* __restrict__ Wa, const float* __restrict__ ba,
    const float* __restrict__ wsc, const float* __restrict__ bsc,
    float* __restrict__ a) {
    int n0 = blockIdx.x * 16;
    int j = threadIdx.x;
    int u = j >> 3, q = j & 7;
    __shared__ float xT[160][16];
    {
        const float4* h4 = (const float4*)(h + (size_t)(n0 + u) * HID);
#pragma unroll
        for (int k = 0; k < 4; k++) {
            float4 v = h4[q + 8 * k];
            xT[32 * k + 4 * q + 0][u] = v.x; xT[32 * k + 4 * q + 1][u] = v.y;
            xT[32 * k + 4 * q + 2][u] = v.z; xT[32 * k + 4 * q + 3][u] = v.w;
        }
        float4 e4 = ((const float4*)(er + (size_t)(n0 + u) * REL_DIM))[q];
        xT[128 + 4 * q + 0][u] = e4.x; xT[128 + 4 * q + 1][u] = e4.y;
        xT[128 + 4 * q + 2][u] = e4.z; xT[128 + 4 * q + 3][u] = e4.w;
    }
    __syncthreads();
    float bj = ba[j];
    float acc[16];
#pragma unroll
    for (int k = 0; k < 16; k++) acc[k] = bj;
    for (int d = 0; d < 160; d++) {
        float w = Wa[d * HID + j];
        float4 x0 = *(const float4*)&xT[d][0];
        float4 x1 = *(const float4*)&xT[d][4];
        float4 x2 = *(const float4*)&xT[d][8];
        float4 x3 = *(const float4*)&xT[d][12];
        acc[0]  = fmaf(x0.x, w, acc[0]);  acc[1]  = fmaf(x0.y, w, acc[1]);
        acc[2]  = fmaf(x0.z, w, acc[2]);  acc[3]  = fmaf(x0.w, w, acc[3]);
        acc[4]  = fmaf(x1.x, w, acc[4]);  acc[5]  = fmaf(x1.y, w, acc[5]);
        acc[6]  = fmaf(x1.z, w, acc[6]);  acc[7]  = fmaf(x1.w, w, acc[7]);
        acc[8]  = fmaf(x2.x, w, acc[8]);  acc[9]  = fmaf(x2.y, w, acc[9]);
        acc[10] = fmaf(x2.z, w, acc[10]); acc[11] = fmaf(x2.w, w, acc[11]);
        acc[12] = fmaf(x3.x, w, acc[12]); acc[13] = fmaf(x3.y, w, acc[13]);
        acc[14] = fmaf(x3.z, w, acc[14]); acc[15] = fmaf(x3.w, w, acc[15]);
    }
    __shared__ float red[16][128];
    float wj = wsc[j];
#pragma unroll
    for (int k = 0; k < 16; k++) red[k][j] = tanhf(acc[k]) * wj;
    __syncthreads();
    for (int s = 64; s > 0; s >>= 1) {
        if (j < s) {
#pragma unroll
            for (int k = 0; k < 16; k++) red[k][j] += red[k][j + s];
        }
        __syncthreads();
    }
    if (j < 16) a[n0 + j] = red[j][0] + bsc[0];
}

// ---------------- graph boundaries (graph_id is sorted) ----------------
__global__ void k_starts(const int* __restrict__ gid, int* __restrict__ starts) {
    int g = threadIdx.x;  // 0..255
    int lo = 0, hi = N_NODES;
    while (lo < hi) {
        int mid = (lo + hi) >> 1;
        if (gid[mid] < g) lo = mid + 1; else hi = mid;
    }
    starts[g] = lo;
    if (g == 0) starts[NUM_GRAPHS] = N_NODES;
}

// ---------------- segment softmax pooling + final dot ----------------
__global__ void __launch_bounds__(128) k_pool(
    const float* __restrict__ h, const float* __restrict__ a,
    const int* __restrict__ starts, const float* __restrict__ wout,
    const float* __restrict__ bout, float* __restrict__ out) {
    int g = blockIdx.x, j = threadIdx.x;
    int s0 = starts[g], s1 = starts[g + 1];
    __shared__ float red[128];
    __shared__ float exb[128];
    if (s1 <= s0) { if (j == 0) out[g] = bout[0]; return; }
    float m = -3.4e38f;
    for (int i = s0 + j; i < s1; i += 128) m = fmaxf(m, a[i]);
    red[j] = m; __syncthreads();
    for (int s = 64; s > 0; s >>= 1) {
        if (j < s) red[j] = fmaxf(red[j], red[j + s]);
        __syncthreads();
    }
    m = red[0]; __syncthreads();
    float zj = 0.f, ss = 0.f;
    for (int base = s0; base < s1; base += 128) {
        int cnt = min(128, s1 - base);
        float ev = 0.f;
        if (j < cnt) ev = expf(a[base + j] - m);
        exb[j] = ev;
        ss += ev;
        __syncthreads();
        for (int k = 0; k < cnt; k++)
            zj = fmaf(exb[k], h[(size_t)(base + k) * HID + j], zj);
        __syncthreads();
    }
    red[j] = ss; __syncthreads();
    for (int s = 64; s > 0; s >>= 1) {
        if (j < s) red[j] += red[j + s];
        __syncthreads();
    }
    ss = red[0]; __syncthreads();
    red[j] = (zj / ss) * wout[j]; __syncthreads();
    for (int s = 64; s > 0; s >>= 1) {
        if (j < s) red[j] += red[j + s];
        __syncthreads();
    }
    if (j == 0) out[g] = red[0] + bout[0];
}

extern "C" void kernel_launch(void* const* d_in, const int* in_sizes, int n_in,
                              void* d_out, int out_size, void* d_ws, size_t ws_size,
                              hipStream_t stream) {
    const float* feat    = (const float*)d_in[0];
    const int*   qrel    = (const int*)d_in[1];
    const int*   src     = (const int*)d_in[2];
    const int*   dst     = (const int*)d_in[3];
    const int*   ety     = (const int*)d_in[4];
    const int*   gid     = (const int*)d_in[5];
    const float* rel_emb = (const float*)d_in[6];
    const float* W_in    = (const float*)d_in[7];
    const float* b_in    = (const float*)d_in[8];
    const float* V       = (const float*)d_in[9];
    const float* comp    = (const float*)d_in[10];
    const float* W_loop  = (const float*)d_in[11];
    const float* b_loop  = (const float*)d_in[12];
    const float* W_attn  = (const float*)d_in[13];
    const float* b_attn  = (const float*)d_in[14];
    const float* w_sc    = (const float*)d_in[15];
    const float* b_sc    = (const float*)d_in[16];
    const float* w_out   = (const float*)d_in[17];
    const float* b_out   = (const float*)d_in[18];
    float* out = (float*)d_out;

    float* ws = (float*)d_ws;
    float* h0 = ws;                                       // 6.4M floats
    float* h1 = h0 + (size_t)N_NODES * HID;               // 6.4M
    unsigned short* h16a = (unsigned short*)(h1 + (size_t)N_NODES * HID);  // 6.4M ushort
    unsigned short* h16b = h16a + (size_t)N_NODES * HID;                   // 6.4M ushort
    float* er = (float*)(h16b + (size_t)N_NODES * HID);   // 1.6M
    float* af = er + (size_t)N_NODES * REL_DIM;           // 50000
    int* starts    = (int*)(af + N_NODES);                // 260
    int* deg       = starts + 260;                        // 50000
    int* row_start = deg + 50000;                         // 50004
    int* cursor    = row_start + 50004;                   // 50000
    int* bsum      = cursor + 50000;                      // 256
    int* boff      = bsum + 256;                          // 256
    int* edge_p    = boff + 256;                          // 800000 packed ints
    unsigned short* Bf = (unsigned short*)(edge_p + 800000);  // 2*36*8*64*16 ushort
    const size_t BF_USHORT = (size_t)NUM_LAYERS * 36 * 8 * 64 * 16;
    unsigned short* Ghi = Bf + BF_USHORT;

    size_t used_floats = (size_t)((float*)Ghi - ws);
    size_t total_floats = ws_size / sizeof(float);
    size_t avail = (total_floats > used_floats) ? (total_floats - used_floats) : 0;
    long long NC = (long long)(avail / 1024);   // rows: 1024 hi + 1024 lo ushorts = 1024 floats
    NC = (NC / 64) * 64;
    if (NC > 50048) NC = 50048;
    if (NC < 64) NC = 64;
    unsigned short* Glo = Ghi + (size_t)NC * 1024;

    // --- preprocessing ---
    k_zero<<<(12500 + 255) / 256, 256, 0, stream>>>((float*)deg, 12500);
    k_hist<<<(N_EDGES + 255) / 256, 256, 0, stream>>>(dst, deg);
    k_scan_a<<<SCAN_BLKS, 256, 0, stream>>>(deg, row_start, bsum);
    k_scan_b<<<1, 256, 0, stream>>>(bsum, boff);
    k_scan_c<<<SCAN_BLKS, 256, 0, stream>>>(row_start, boff, cursor);
    k_scatter<<<(N_EDGES + 255) / 256, 256, 0, stream>>>(src, dst, ety, cursor, edge_p);
    k_bfrag<<<(NUM_LAYERS * 36 * 8 * 64 + 255) / 256, 256, 0, stream>>>(V, W_loop, Bf);
    k_input<<<N_NODES / 16, 128, 0, stream>>>(feat, qrel, rel_emb, W_in, b_in, h0, h16a, er);

    float* hcur = h0;
    float* hnext = h1;
    unsigned short* h16cur = h16a;
    unsigned short* h16next = h16b;
    for (int l = 0; l < NUM_LAYERS; l++) {
        const float* comp_l = comp + (size_t)l * NUM_RELS * NUM_BASES;
        const unsigned short* Bfl = Bf + (size_t)l * 36 * 8 * 64 * 16;
        const float* bl = b_loop + (size_t)l * HID;
        for (int c0 = 0; c0 < N_NODES; c0 += (int)NC) {
            int nc = (int)((N_NODES - c0 < NC) ? (N_NODES - c0) : NC);
            k_mix2<<<(nc + 3) / 4, 256, 0, stream>>>(h16cur, comp_l, row_start, edge_p,
                                                     Ghi, Glo, c0, nc);
            k_gemm6<<<(nc + 63) / 64, 256, 0, stream>>>(Ghi, Glo, hcur, Bfl, bl,
                                                        hnext, h16next, c0, nc);
        }
        float* tmp = hcur; hcur = hnext; hnext = tmp;
        unsigned short* tmp16 = h16cur; h16cur = h16next; h16next = tmp16;
    }

    k_score<<<N_NODES / 16, 128, 0, stream>>>(hcur, er, W_attn, b_attn, w_sc, b_sc, af);
    k_starts<<<1, 256, 0, stream>>>(gid, starts);
    k_pool<<<NUM_GRAPHS, 128, 0, stream>>>(hcur, af, starts, w_out, b_out, out);
}

// Round 11
// 501.889 us; speedup vs baseline: 1.2586x; 1.2586x over previous
//
#include <hip/hip_runtime.h>
#include <hip/hip_fp16.h>

#define N_NODES   50000
#define N_EDGES   800000
#define NUM_GRAPHS 256
#define IN_FEAT   64
#define REL_DIM   32
#define HID       128
#define NUM_RELS  32
#define NUM_BASES 8
#define NUM_LAYERS 2

#define SCAN_BLKS ((N_NODES + 255) / 256)   // 196

typedef __attribute__((ext_vector_type(8))) _Float16 f16x8;
typedef __attribute__((ext_vector_type(4))) float f32x4;

// async 16B global -> LDS (wave-uniform LDS base + lane*16; per-lane global src)
__device__ __forceinline__ void gld_lds16(void* lds, const void* g) {
    __builtin_amdgcn_global_load_lds(
        (const __attribute__((address_space(1))) unsigned int*)g,
        (__attribute__((address_space(3))) unsigned int*)lds, 16, 0, 0);
}

// ---------------- zero (float4 granularity) ----------------
__global__ void k_zero(float* __restrict__ p, int n4) {
    int i = blockIdx.x * 256 + threadIdx.x;
    if (i < n4) ((float4*)p)[i] = make_float4(0.f, 0.f, 0.f, 0.f);
}

// ---------------- CSR build: histogram, 3-phase scan, scatter ----------------
__global__ void k_hist(const int* __restrict__ dst, int* __restrict__ deg) {
    int e = blockIdx.x * 256 + threadIdx.x;
    if (e < N_EDGES) atomicAdd(&deg[dst[e]], 1);
}

__global__ void __launch_bounds__(256) k_scan_a(
    const int* __restrict__ deg, int* __restrict__ row_start, int* __restrict__ bsum) {
    __shared__ int s[256];
    int t = threadIdx.x;
    int idx = blockIdx.x * 256 + t;
    int v = (idx < N_NODES) ? deg[idx] : 0;
    s[t] = v;
    __syncthreads();
    for (int off = 1; off < 256; off <<= 1) {
        int u = (t >= off) ? s[t - off] : 0;
        __syncthreads();
        s[t] += u;
        __syncthreads();
    }
    if (idx < N_NODES) row_start[idx] = s[t] - v;   // local exclusive
    if (t == 255) bsum[blockIdx.x] = s[255];
}

__global__ void __launch_bounds__(256) k_scan_b(int* __restrict__ bsum,
                                                int* __restrict__ boff) {
    __shared__ int s[256];
    int t = threadIdx.x;
    int v = (t < SCAN_BLKS) ? bsum[t] : 0;
    s[t] = v;
    __syncthreads();
    for (int off = 1; off < 256; off <<= 1) {
        int u = (t >= off) ? s[t - off] : 0;
        __syncthreads();
        s[t] += u;
        __syncthreads();
    }
    if (t < SCAN_BLKS) boff[t] = s[t] - v;          // exclusive
}

__global__ void __launch_bounds__(256) k_scan_c(
    int* __restrict__ row_start, const int* __restrict__ boff,
    int* __restrict__ cursor) {
    int idx = blockIdx.x * 256 + threadIdx.x;
    if (idx < N_NODES) {
        int r = row_start[idx] + boff[blockIdx.x];
        row_start[idx] = r;
        cursor[idx] = r;
    }
    if (idx == 0) row_start[N_NODES] = N_EDGES;
}

// packed payload: (src << 5) | ety   (src < 2^17, ety < 32)
__global__ void k_scatter(const int* __restrict__ src, const int* __restrict__ dst,
                          const int* __restrict__ ety, int* __restrict__ cursor,
                          int* __restrict__ edge_p) {
    int e = blockIdx.x * 256 + threadIdx.x;
    if (e >= N_EDGES) return;
    int d = dst[e];
    int pos = atomicAdd(&cursor[d], 1);
    edge_p[pos] = (src[e] << 5) | ety[e];
}

// ---------------- input projection (16 nodes/block): h = relu([feat, er] @ W_in + b_in) ----------------
__global__ void __launch_bounds__(128) k_input(
    const float* __restrict__ feat, const int* __restrict__ qrel,
    const float* __restrict__ rel_emb, const float* __restrict__ Wi,
    const float* __restrict__ bi, float* __restrict__ h,
    unsigned short* __restrict__ h16, float* __restrict__ er) {
    int n0 = blockIdx.x * 16;
    int j = threadIdx.x;
    int u = j >> 3, q = j & 7;
    __shared__ float xT[96][16];
    {
        const float4* f4 = (const float4*)(feat + (size_t)(n0 + u) * IN_FEAT);
        float4 a = f4[q], b = f4[q + 8];
        xT[4 * q + 0][u] = a.x; xT[4 * q + 1][u] = a.y;
        xT[4 * q + 2][u] = a.z; xT[4 * q + 3][u] = a.w;
        xT[32 + 4 * q + 0][u] = b.x; xT[32 + 4 * q + 1][u] = b.y;
        xT[32 + 4 * q + 2][u] = b.z; xT[32 + 4 * q + 3][u] = b.w;
        int qr = qrel[n0 + u];
        float4 e4 = ((const float4*)(rel_emb + (size_t)qr * REL_DIM))[q];
        xT[64 + 4 * q + 0][u] = e4.x; xT[64 + 4 * q + 1][u] = e4.y;
        xT[64 + 4 * q + 2][u] = e4.z; xT[64 + 4 * q + 3][u] = e4.w;
        ((float4*)(er + (size_t)(n0 + u) * REL_DIM))[q] = e4;
    }
    __syncthreads();
    float bj = bi[j];
    float acc[16];
#pragma unroll
    for (int k = 0; k < 16; k++) acc[k] = bj;
    for (int d = 0; d < 96; d++) {
        float w = Wi[d * HID + j];
        float4 x0 = *(const float4*)&xT[d][0];
        float4 x1 = *(const float4*)&xT[d][4];
        float4 x2 = *(const float4*)&xT[d][8];
        float4 x3 = *(const float4*)&xT[d][12];
        acc[0]  = fmaf(x0.x, w, acc[0]);  acc[1]  = fmaf(x0.y, w, acc[1]);
        acc[2]  = fmaf(x0.z, w, acc[2]);  acc[3]  = fmaf(x0.w, w, acc[3]);
        acc[4]  = fmaf(x1.x, w, acc[4]);  acc[5]  = fmaf(x1.y, w, acc[5]);
        acc[6]  = fmaf(x1.z, w, acc[6]);  acc[7]  = fmaf(x1.w, w, acc[7]);
        acc[8]  = fmaf(x2.x, w, acc[8]);  acc[9]  = fmaf(x2.y, w, acc[9]);
        acc[10] = fmaf(x2.z, w, acc[10]); acc[11] = fmaf(x2.w, w, acc[11]);
        acc[12] = fmaf(x3.x, w, acc[12]); acc[13] = fmaf(x3.y, w, acc[13]);
        acc[14] = fmaf(x3.z, w, acc[14]); acc[15] = fmaf(x3.w, w, acc[15]);
    }
#pragma unroll
    for (int k = 0; k < 16; k++) {
        float v = fmaxf(acc[k], 0.f);
        h[(size_t)(n0 + k) * HID + j] = v;
        __half hv = __float2half(v);
        h16[(size_t)(n0 + k) * HID + j] = __builtin_bit_cast(unsigned short, hv);
    }
}

// ---------------- per-dst basis-weighted gather (fp16 h), fp16 G output ----------------
// Gf[n-c0][b*128+d] = fp16( sum_e c[ety,b]*h16[src,d] )
__global__ void __launch_bounds__(256) k_mix2(
    const unsigned short* __restrict__ h16, const float* __restrict__ comp_l,
    const int* __restrict__ row_start, const int* __restrict__ edge_p,
    unsigned short* __restrict__ Gf, int c0, int nc) {
    __shared__ float cs[NUM_RELS * NUM_BASES];
    if (threadIdx.x < NUM_RELS * NUM_BASES) cs[threadIdx.x] = comp_l[threadIdx.x];
    __syncthreads();
    int wave = threadIdx.x >> 6, lane = threadIdx.x & 63;
    int n = c0 + blockIdx.x * 4 + wave;
    if (n >= c0 + nc) return;
    int e0 = row_start[n], e1 = row_start[n + 1];
    float2 acc[NUM_BASES];
#pragma unroll
    for (int b = 0; b < NUM_BASES; b++) acc[b] = make_float2(0.f, 0.f);
    for (int e = e0; e < e1; e++) {
        int se = edge_p[e];
        const float* c = &cs[(se & 31) * NUM_BASES];
        unsigned u = ((const unsigned*)(h16 + (size_t)(se >> 5) * HID))[lane];
        __half2 hh = __builtin_bit_cast(__half2, u);
        float2 v = __half22float2(hh);
#pragma unroll
        for (int b = 0; b < NUM_BASES; b++) {
            acc[b].x = fmaf(c[b], v.x, acc[b].x);
            acc[b].y = fmaf(c[b], v.y, acc[b].y);
        }
    }
    size_t base = (size_t)(n - c0) * 1024 + 2 * lane;
#pragma unroll
    for (int b = 0; b < NUM_BASES; b++) {
        __half2 g2 = __floats2half2_rn(acc[b].x, acc[b].y);
        *(unsigned*)&Gf[base + b * 128] = __builtin_bit_cast(unsigned, g2);
    }
}

// ---------------- B fragment table: f16 hi + f16 (lo*4096) of [Vl ; Wl], MFMA fragment order ----------------
// entry (l, s, t, lane): 16 ushort = hi[8], lo[8];
// element j: B[k = s*32 + (lane>>4)*8 + j][col = t*16 + (lane&15)] of layer l.
__global__ void k_bfrag(const float* __restrict__ V, const float* __restrict__ W_loop,
                        unsigned short* __restrict__ Bf) {
    int idx = blockIdx.x * 256 + threadIdx.x;
    if (idx >= NUM_LAYERS * 36 * 8 * 64) return;
    int lane = idx & 63;
    int t = (idx >> 6) & 7;
    int s = (idx >> 9) % 36;
    int l = (idx >> 9) / 36;
    int col = t * 16 + (lane & 15);
    int kbase = s * 32 + (lane >> 4) * 8;
    unsigned short* o = Bf + (size_t)idx * 16;
#pragma unroll
    for (int j = 0; j < 8; j++) {
        int k = kbase + j;
        float f = (k < 1024) ? V[((size_t)l * 1024 + k) * HID + col]
                             : W_loop[((size_t)l * HID + (k - 1024)) * HID + col];
        __half hh = __float2half(f);
        float res = (f - __half2float(hh)) * 4096.f;
        __half hl = __float2half(res);
        o[j] = __builtin_bit_cast(unsigned short, hh);
        o[8 + j] = __builtin_bit_cast(unsigned short, hl);
    }
}

// ---------------- f16 MFMA GEMM (BM=32, BK=64), global_load_lds dbuf A staging ----------------
// out = relu([G | h] @ [Vl ; Wl] + bl); also fp16 copy.  M=nc, K=1152, N=128.
// A is fp16 (G / h16 direct); B = Bh + Bl/4096 via dual accumulators (2 MFMA/tile).
// Block = 32 rows x 128 cols, 4 waves col-split (wave w -> t=2w,2w+1).
// LDS: 2 bufs x 4 frags (2 k-subtiles x 2 rowgroups) x 1KB = 8KB, lane-linear.
__global__ void __launch_bounds__(256) k_gemm7(
    const unsigned short* __restrict__ Gf, const unsigned short* __restrict__ h16,
    const unsigned short* __restrict__ Bf, const float* __restrict__ bl,
    float* __restrict__ out, unsigned short* __restrict__ out16, int c0, int nc) {
    __shared__ unsigned short smem[2][4][512];  // [buf][frag][1KB]
    int lane = threadIdx.x & 63;
    int w = threadIdx.x >> 6;
    int rit = lane & 15, kg = lane >> 4;
    int r0 = blockIdx.x * 32;
    // staging role: wave w stages frag F = (st_s*2 + st_i), st_i = w&1 rowgroup, st_s = w>>1 k-subtile
    int st_i = w & 1, st_s = w >> 1;
    int st_row = r0 + st_i * 16 + rit; if (st_row >= nc) st_row = nc - 1;
    const unsigned short* gsrc = Gf + (size_t)st_row * 1024 + st_s * 32 + kg * 8;
    const f16x8* bb = (const f16x8*)Bf + ((size_t)(2 * w) * 64 + lane) * 2;
    f32x4 ah00 = {}, ah01 = {}, ah10 = {}, ah11 = {};
    f32x4 al00 = {}, al01 = {}, al10 = {}, al11 = {};

#define STAGE(BUF, STEP) \
        gld_lds16(&smem[BUF][st_s * 2 + st_i][0], gsrc + (STEP) * 64);
#define CSTEP(BUF, STEP) _Pragma("unroll")                                   \
    for (int s = 0; s < 2; s++) {                                            \
        const f16x8* bp = bb + (size_t)((STEP) * 2 + s) * 1024;              \
        f16x8 bh0 = bp[0], bq0 = bp[1], bh1 = bp[128], bq1 = bp[129];        \
        f16x8 a0 = *(const f16x8*)&smem[BUF][s * 2 + 0][lane * 8];           \
        f16x8 a1 = *(const f16x8*)&smem[BUF][s * 2 + 1][lane * 8];           \
        ah00 = __builtin_amdgcn_mfma_f32_16x16x32_f16(a0, bh0, ah00, 0, 0, 0); \
        al00 = __builtin_amdgcn_mfma_f32_16x16x32_f16(a0, bq0, al00, 0, 0, 0); \
        ah01 = __builtin_amdgcn_mfma_f32_16x16x32_f16(a0, bh1, ah01, 0, 0, 0); \
        al01 = __builtin_amdgcn_mfma_f32_16x16x32_f16(a0, bq1, al01, 0, 0, 0); \
        ah10 = __builtin_amdgcn_mfma_f32_16x16x32_f16(a1, bh0, ah10, 0, 0, 0); \
        al10 = __builtin_amdgcn_mfma_f32_16x16x32_f16(a1, bq0, al10, 0, 0, 0); \
        ah11 = __builtin_amdgcn_mfma_f32_16x16x32_f16(a1, bh1, ah11, 0, 0, 0); \
        al11 = __builtin_amdgcn_mfma_f32_16x16x32_f16(a1, bq1, al11, 0, 0, 0); \
    }

    STAGE(0, 0);
    for (int t = 0; t < 16; t++) {
        __syncthreads();
        if (t < 15) STAGE((t + 1) & 1, t + 1);
        CSTEP(t & 1, t);
    }
    // K tail 1024..1151 (self-loop) straight from fp16 h16
    {
        int rT0 = r0 + rit;      if (rT0 >= nc) rT0 = nc - 1;
        int rT1 = r0 + 16 + rit; if (rT1 >= nc) rT1 = nc - 1;
        const unsigned short* hp0 = h16 + (size_t)(c0 + rT0) * HID + kg * 8;
        const unsigned short* hp1 = h16 + (size_t)(c0 + rT1) * HID + kg * 8;
#pragma unroll
        for (int s = 32; s < 36; s++) {
            int o = (s - 32) * 32;
            f16x8 a0 = *(const f16x8*)(hp0 + o);
            f16x8 a1 = *(const f16x8*)(hp1 + o);
            const f16x8* bp = bb + (size_t)s * 1024;
            f16x8 bh0 = bp[0], bq0 = bp[1], bh1 = bp[128], bq1 = bp[129];
            ah00 = __builtin_amdgcn_mfma_f32_16x16x32_f16(a0, bh0, ah00, 0, 0, 0);
            al00 = __builtin_amdgcn_mfma_f32_16x16x32_f16(a0, bq0, al00, 0, 0, 0);
            ah01 = __builtin_amdgcn_mfma_f32_16x16x32_f16(a0, bh1, ah01, 0, 0, 0);
            al01 = __builtin_amdgcn_mfma_f32_16x16x32_f16(a0, bq1, al01, 0, 0, 0);
            ah10 = __builtin_amdgcn_mfma_f32_16x16x32_f16(a1, bh0, ah10, 0, 0, 0);
            al10 = __builtin_amdgcn_mfma_f32_16x16x32_f16(a1, bq0, al10, 0, 0, 0);
            ah11 = __builtin_amdgcn_mfma_f32_16x16x32_f16(a1, bh1, ah11, 0, 0, 0);
            al11 = __builtin_amdgcn_mfma_f32_16x16x32_f16(a1, bq1, al11, 0, 0, 0);
        }
    }
#undef STAGE
#undef CSTEP
    const float INV = 1.f / 4096.f;
    int col0 = 2 * w * 16 + rit;
    float b0 = bl[col0], b1 = bl[col0 + 16];
    int rq = r0 + kg * 4;
#pragma unroll
    for (int q = 0; q < 4; q++) {
        int rA = rq + q;
        if (rA < nc) {
            float v0 = fmaxf(fmaf(al00[q], INV, ah00[q]) + b0, 0.f);
            float v1 = fmaxf(fmaf(al01[q], INV, ah01[q]) + b1, 0.f);
            size_t o = (size_t)(c0 + rA) * HID;
            out[o + col0] = v0; out[o + col0 + 16] = v1;
            out16[o + col0] = __builtin_bit_cast(unsigned short, __float2half(v0));
            out16[o + col0 + 16] = __builtin_bit_cast(unsigned short, __float2half(v1));
        }
        int rB = rA + 16;
        if (rB < nc) {
            float v0 = fmaxf(fmaf(al10[q], INV, ah10[q]) + b0, 0.f);
            float v1 = fmaxf(fmaf(al11[q], INV, ah11[q]) + b1, 0.f);
            size_t o = (size_t)(c0 + rB) * HID;
            out[o + col0] = v0; out[o + col0 + 16] = v1;
            out16[o + col0] = __builtin_bit_cast(unsigned short, __float2half(v0));
            out16[o + col0 + 16] = __builtin_bit_cast(unsigned short, __float2half(v1));
        }
    }
}

// ---------------- attention scalar score per node (16 nodes/block) ----------------
__global__ void __launch_bounds__(128) k_score(
    const float* __restrict__ h, const float* __restrict__ er,
    const float* __restrict__ Wa, const float* __restrict__ ba,
    const float* __restrict__ wsc, const float* __restrict__ bsc,
    float* __restrict__ a) {
    int n0 = blockIdx.x * 16;
    int j = threadIdx.x;
    int u = j >> 3, q = j & 7;
    __shared__ float xT[160][16];
    {
        const float4* h4 = (const float4*)(h + (size_t)(n0 + u) * HID);
#pragma unroll
        for (int k = 0; k < 4; k++) {
            float4 v = h4[q + 8 * k];
            xT[32 * k + 4 * q + 0][u] = v.x; xT[32 * k + 4 * q + 1][u] = v.y;
            xT[32 * k + 4 * q + 2][u] = v.z; xT[32 * k + 4 * q + 3][u] = v.w;
        }
        float4 e4 = ((const float4*)(er + (size_t)(n0 + u) * REL_DIM))[q];
        xT[128 + 4 * q + 0][u] = e4.x; xT[128 + 4 * q + 1][u] = e4.y;
        xT[128 + 4 * q + 2][u] = e4.z; xT[128 + 4 * q + 3][u] = e4.w;
    }
    __syncthreads();
    float bj = ba[j];
    float acc[16];
#pragma unroll
    for (int k = 0; k < 16; k++) acc[k] = bj;
    for (int d = 0; d < 160; d++) {
        float w = Wa[d * HID + j];
        float4 x0 = *(const float4*)&xT[d][0];
        float4 x1 = *(const float4*)&xT[d][4];
        float4 x2 = *(const float4*)&xT[d][8];
        float4 x3 = *(const float4*)&xT[d][12];
        acc[0]  = fmaf(x0.x, w, acc[0]);  acc[1]  = fmaf(x0.y, w, acc[1]);
        acc[2]  = fmaf(x0.z, w, acc[2]);  acc[3]  = fmaf(x0.w, w, acc[3]);
        acc[4]  = fmaf(x1.x, w, acc[4]);  acc[5]  = fmaf(x1.y, w, acc[5]);
        acc[6]  = fmaf(x1.z, w, acc[6]);  acc[7]  = fmaf(x1.w, w, acc[7]);
        acc[8]  = fmaf(x2.x, w, acc[8]);  acc[9]  = fmaf(x2.y, w, acc[9]);
        acc[10] = fmaf(x2.z, w, acc[10]); acc[11] = fmaf(x2.w, w, acc[11]);
        acc[12] = fmaf(x3.x, w, acc[12]); acc[13] = fmaf(x3.y, w, acc[13]);
        acc[14] = fmaf(x3.z, w, acc[14]); acc[15] = fmaf(x3.w, w, acc[15]);
    }
    __shared__ float red[16][128];
    float wj = wsc[j];
#pragma unroll
    for (int k = 0; k < 16; k++) red[k][j] = tanhf(acc[k]) * wj;
    __syncthreads();
    for (int s = 64; s > 0; s >>= 1) {
        if (j < s) {
#pragma unroll
            for (int k = 0; k < 16; k++) red[k][j] += red[k][j + s];
        }
        __syncthreads();
    }
    if (j < 16) a[n0 + j] = red[j][0] + bsc[0];
}

// ---------------- graph boundaries (graph_id is sorted) ----------------
__global__ void k_starts(const int* __restrict__ gid, int* __restrict__ starts) {
    int g = threadIdx.x;  // 0..255
    int lo = 0, hi = N_NODES;
    while (lo < hi) {
        int mid = (lo + hi) >> 1;
        if (gid[mid] < g) lo = mid + 1; else hi = mid;
    }
    starts[g] = lo;
    if (g == 0) starts[NUM_GRAPHS] = N_NODES;
}

// ---------------- segment softmax pooling + final dot ----------------
__global__ void __launch_bounds__(128) k_pool(
    const float* __restrict__ h, const float* __restrict__ a,
    const int* __restrict__ starts, const float* __restrict__ wout,
    const float* __restrict__ bout, float* __restrict__ out) {
    int g = blockIdx.x, j = threadIdx.x;
    int s0 = starts[g], s1 = starts[g + 1];
    __shared__ float red[128];
    __shared__ float exb[128];
    if (s1 <= s0) { if (j == 0) out[g] = bout[0]; return; }
    float m = -3.4e38f;
    for (int i = s0 + j; i < s1; i += 128) m = fmaxf(m, a[i]);
    red[j] = m; __syncthreads();
    for (int s = 64; s > 0; s >>= 1) {
        if (j < s) red[j] = fmaxf(red[j], red[j + s]);
        __syncthreads();
    }
    m = red[0]; __syncthreads();
    float zj = 0.f, ss = 0.f;
    for (int base = s0; base < s1; base += 128) {
        int cnt = min(128, s1 - base);
        float ev = 0.f;
        if (j < cnt) ev = expf(a[base + j] - m);
        exb[j] = ev;
        ss += ev;
        __syncthreads();
        for (int k = 0; k < cnt; k++)
            zj = fmaf(exb[k], h[(size_t)(base + k) * HID + j], zj);
        __syncthreads();
    }
    red[j] = ss; __syncthreads();
    for (int s = 64; s > 0; s >>= 1) {
        if (j < s) red[j] += red[j + s];
        __syncthreads();
    }
    ss = red[0]; __syncthreads();
    red[j] = (zj / ss) * wout[j]; __syncthreads();
    for (int s = 64; s > 0; s >>= 1) {
        if (j < s) red[j] += red[j + s];
        __syncthreads();
    }
    if (j == 0) out[g] = red[0] + bout[0];
}

extern "C" void kernel_launch(void* const* d_in, const int* in_sizes, int n_in,
                              void* d_out, int out_size, void* d_ws, size_t ws_size,
                              hipStream_t stream) {
    const float* feat    = (const float*)d_in[0];
    const int*   qrel    = (const int*)d_in[1];
    const int*   src     = (const int*)d_in[2];
    const int*   dst     = (const int*)d_in[3];
    const int*   ety     = (const int*)d_in[4];
    const int*   gid     = (const int*)d_in[5];
    const float* rel_emb = (const float*)d_in[6];
    const float* W_in    = (const float*)d_in[7];
    const float* b_in    = (const float*)d_in[8];
    const float* V       = (const float*)d_in[9];
    const float* comp    = (const float*)d_in[10];
    const float* W_loop  = (const float*)d_in[11];
    const float* b_loop  = (const float*)d_in[12];
    const float* W_attn  = (const float*)d_in[13];
    const float* b_attn  = (const float*)d_in[14];
    const float* w_sc    = (const float*)d_in[15];
    const float* b_sc    = (const float*)d_in[16];
    const float* w_out   = (const float*)d_in[17];
    const float* b_out   = (const float*)d_in[18];
    float* out = (float*)d_out;

    float* ws = (float*)d_ws;
    float* h0 = ws;                                       // 6.4M floats
    float* h1 = h0 + (size_t)N_NODES * HID;               // 6.4M
    unsigned short* h16a = (unsigned short*)(h1 + (size_t)N_NODES * HID);  // 6.4M ushort
    unsigned short* h16b = h16a + (size_t)N_NODES * HID;                   // 6.4M ushort
    float* er = (float*)(h16b + (size_t)N_NODES * HID);   // 1.6M
    float* af = er + (size_t)N_NODES * REL_DIM;           // 50000
    int* starts    = (int*)(af + N_NODES);                // 260
    int* deg       = starts + 260;                        // 50000
    int* row_start = deg + 50000;                         // 50004
    int* cursor    = row_start + 50004;                   // 50000
    int* bsum      = cursor + 50000;                      // 256
    int* boff      = bsum + 256;                          // 256
    int* edge_p    = boff + 256;                          // 800000 packed ints
    unsigned short* Bf = (unsigned short*)(edge_p + 800000);  // 2*36*8*64*16 ushort
    const size_t BF_USHORT = (size_t)NUM_LAYERS * 36 * 8 * 64 * 16;
    unsigned short* Gf = Bf + BF_USHORT;

    size_t used_floats = (size_t)((float*)Gf - ws);
    size_t total_floats = ws_size / sizeof(float);
    size_t avail = (total_floats > used_floats) ? (total_floats - used_floats) : 0;
    long long NC = (long long)(avail / 512);   // 1024 fp16 per row = 512 floats
    NC = (NC / 64) * 64;
    if (NC > 50048) NC = 50048;
    if (NC < 64) NC = 64;

    // --- preprocessing ---
    k_zero<<<(12500 + 255) / 256, 256, 0, stream>>>((float*)deg, 12500);
    k_hist<<<(N_EDGES + 255) / 256, 256, 0, stream>>>(dst, deg);
    k_scan_a<<<SCAN_BLKS, 256, 0, stream>>>(deg, row_start, bsum);
    k_scan_b<<<1, 256, 0, stream>>>(bsum, boff);
    k_scan_c<<<SCAN_BLKS, 256, 0, stream>>>(row_start, boff, cursor);
    k_scatter<<<(N_EDGES + 255) / 256, 256, 0, stream>>>(src, dst, ety, cursor, edge_p);
    k_bfrag<<<(NUM_LAYERS * 36 * 8 * 64 + 255) / 256, 256, 0, stream>>>(V, W_loop, Bf);
    k_input<<<N_NODES / 16, 128, 0, stream>>>(feat, qrel, rel_emb, W_in, b_in, h0, h16a, er);

    float* hcur = h0;
    float* hnext = h1;
    unsigned short* h16cur = h16a;
    unsigned short* h16next = h16b;
    for (int l = 0; l < NUM_LAYERS; l++) {
        const float* comp_l = comp + (size_t)l * NUM_RELS * NUM_BASES;
        const unsigned short* Bfl = Bf + (size_t)l * 36 * 8 * 64 * 16;
        const float* bl = b_loop + (size_t)l * HID;
        for (int c0 = 0; c0 < N_NODES; c0 += (int)NC) {
            int nc = (int)((N_NODES - c0 < NC) ? (N_NODES - c0) : NC);
            k_mix2<<<(nc + 3) / 4, 256, 0, stream>>>(h16cur, comp_l, row_start, edge_p,
                                                     Gf, c0, nc);
            k_gemm7<<<(nc + 31) / 32, 256, 0, stream>>>(Gf, h16cur, Bfl, bl,
                                                        hnext, h16next, c0, nc);
        }
        float* tmp = hcur; hcur = hnext; hnext = tmp;
        unsigned short* tmp16 = h16cur; h16cur = h16next; h16next = tmp16;
    }

    k_score<<<N_NODES / 16, 128, 0, stream>>>(hcur, er, W_attn, b_attn, w_sc, b_sc, af);
    k_starts<<<1, 256, 0, stream>>>(gid, starts);
    k_pool<<<NUM_GRAPHS, 128, 0, stream>>>(hcur, af, starts, w_out, b_out, out);
}

// Round 12
// 417.373 us; speedup vs baseline: 1.5135x; 1.2025x over previous
//
#include <hip/hip_runtime.h>
#include <hip/hip_fp16.h>

#define N_NODES   50000
#define N_EDGES   800000
#define NUM_GRAPHS 256
#define IN_FEAT   64
#define REL_DIM   32
#define HID       128
#define NUM_RELS  32
#define NUM_BASES 8
#define NUM_LAYERS 2

#define SCAN_BLKS ((N_NODES + 255) / 256)   // 196

typedef __attribute__((ext_vector_type(8))) _Float16 f16x8;
typedef __attribute__((ext_vector_type(4))) float f32x4;

// async 16B global -> LDS (wave-uniform LDS base + lane*16; per-lane global src)
__device__ __forceinline__ void gld_lds16(void* lds, const void* g) {
    __builtin_amdgcn_global_load_lds(
        (const __attribute__((address_space(1))) unsigned int*)g,
        (__attribute__((address_space(3))) unsigned int*)lds, 16, 0, 0);
}

// ---------------- zero (float4 granularity) ----------------
__global__ void k_zero(float* __restrict__ p, int n4) {
    int i = blockIdx.x * 256 + threadIdx.x;
    if (i < n4) ((float4*)p)[i] = make_float4(0.f, 0.f, 0.f, 0.f);
}

// ---------------- CSR build: histogram, 3-phase scan, scatter ----------------
__global__ void k_hist(const int* __restrict__ dst, int* __restrict__ deg) {
    int e = blockIdx.x * 256 + threadIdx.x;
    if (e < N_EDGES) atomicAdd(&deg[dst[e]], 1);
}

__global__ void __launch_bounds__(256) k_scan_a(
    const int* __restrict__ deg, int* __restrict__ row_start, int* __restrict__ bsum) {
    __shared__ int s[256];
    int t = threadIdx.x;
    int idx = blockIdx.x * 256 + t;
    int v = (idx < N_NODES) ? deg[idx] : 0;
    s[t] = v;
    __syncthreads();
    for (int off = 1; off < 256; off <<= 1) {
        int u = (t >= off) ? s[t - off] : 0;
        __syncthreads();
        s[t] += u;
        __syncthreads();
    }
    if (idx < N_NODES) row_start[idx] = s[t] - v;   // local exclusive
    if (t == 255) bsum[blockIdx.x] = s[255];
}

__global__ void __launch_bounds__(256) k_scan_b(int* __restrict__ bsum,
                                                int* __restrict__ boff) {
    __shared__ int s[256];
    int t = threadIdx.x;
    int v = (t < SCAN_BLKS) ? bsum[t] : 0;
    s[t] = v;
    __syncthreads();
    for (int off = 1; off < 256; off <<= 1) {
        int u = (t >= off) ? s[t - off] : 0;
        __syncthreads();
        s[t] += u;
        __syncthreads();
    }
    if (t < SCAN_BLKS) boff[t] = s[t] - v;          // exclusive
}

__global__ void __launch_bounds__(256) k_scan_c(
    int* __restrict__ row_start, const int* __restrict__ boff,
    int* __restrict__ cursor) {
    int idx = blockIdx.x * 256 + threadIdx.x;
    if (idx < N_NODES) {
        int r = row_start[idx] + boff[blockIdx.x];
        row_start[idx] = r;
        cursor[idx] = r;
    }
    if (idx == 0) row_start[N_NODES] = N_EDGES;
}

// packed payload: (src << 5) | ety   (src < 2^17, ety < 32)
__global__ void k_scatter(const int* __restrict__ src, const int* __restrict__ dst,
                          const int* __restrict__ ety, int* __restrict__ cursor,
                          int* __restrict__ edge_p) {
    int e = blockIdx.x * 256 + threadIdx.x;
    if (e >= N_EDGES) return;
    int d = dst[e];
    int pos = atomicAdd(&cursor[d], 1);
    edge_p[pos] = (src[e] << 5) | ety[e];
}

// ---------------- input projection (16 nodes/block): h = relu([feat, er] @ W_in + b_in) ----------------
__global__ void __launch_bounds__(128) k_input(
    const float* __restrict__ feat, const int* __restrict__ qrel,
    const float* __restrict__ rel_emb, const float* __restrict__ Wi,
    const float* __restrict__ bi, float* __restrict__ h,
    unsigned short* __restrict__ h16, float* __restrict__ er) {
    int n0 = blockIdx.x * 16;
    int j = threadIdx.x;
    int u = j >> 3, q = j & 7;
    __shared__ float xT[96][16];
    {
        const float4* f4 = (const float4*)(feat + (size_t)(n0 + u) * IN_FEAT);
        float4 a = f4[q], b = f4[q + 8];
        xT[4 * q + 0][u] = a.x; xT[4 * q + 1][u] = a.y;
        xT[4 * q + 2][u] = a.z; xT[4 * q + 3][u] = a.w;
        xT[32 + 4 * q + 0][u] = b.x; xT[32 + 4 * q + 1][u] = b.y;
        xT[32 + 4 * q + 2][u] = b.z; xT[32 + 4 * q + 3][u] = b.w;
        int qr = qrel[n0 + u];
        float4 e4 = ((const float4*)(rel_emb + (size_t)qr * REL_DIM))[q];
        xT[64 + 4 * q + 0][u] = e4.x; xT[64 + 4 * q + 1][u] = e4.y;
        xT[64 + 4 * q + 2][u] = e4.z; xT[64 + 4 * q + 3][u] = e4.w;
        ((float4*)(er + (size_t)(n0 + u) * REL_DIM))[q] = e4;
    }
    __syncthreads();
    float bj = bi[j];
    float acc[16];
#pragma unroll
    for (int k = 0; k < 16; k++) acc[k] = bj;
    for (int d = 0; d < 96; d++) {
        float w = Wi[d * HID + j];
        float4 x0 = *(const float4*)&xT[d][0];
        float4 x1 = *(const float4*)&xT[d][4];
        float4 x2 = *(const float4*)&xT[d][8];
        float4 x3 = *(const float4*)&xT[d][12];
        acc[0]  = fmaf(x0.x, w, acc[0]);  acc[1]  = fmaf(x0.y, w, acc[1]);
        acc[2]  = fmaf(x0.z, w, acc[2]);  acc[3]  = fmaf(x0.w, w, acc[3]);
        acc[4]  = fmaf(x1.x, w, acc[4]);  acc[5]  = fmaf(x1.y, w, acc[5]);
        acc[6]  = fmaf(x1.z, w, acc[6]);  acc[7]  = fmaf(x1.w, w, acc[7]);
        acc[8]  = fmaf(x2.x, w, acc[8]);  acc[9]  = fmaf(x2.y, w, acc[9]);
        acc[10] = fmaf(x2.z, w, acc[10]); acc[11] = fmaf(x2.w, w, acc[11]);
        acc[12] = fmaf(x3.x, w, acc[12]); acc[13] = fmaf(x3.y, w, acc[13]);
        acc[14] = fmaf(x3.z, w, acc[14]); acc[15] = fmaf(x3.w, w, acc[15]);
    }
#pragma unroll
    for (int k = 0; k < 16; k++) {
        float v = fmaxf(acc[k], 0.f);
        h[(size_t)(n0 + k) * HID + j] = v;
        __half hv = __float2half(v);
        h16[(size_t)(n0 + k) * HID + j] = __builtin_bit_cast(unsigned short, hv);
    }
}

// ---------------- per-dst basis-weighted gather (fp16 h), 4-deep MLP, fp16 G output ----------------
// Gf[n-c0][b*128+d] = fp16( sum_e c[ety,b]*h16[src,d] )
__global__ void __launch_bounds__(256) k_mix2(
    const unsigned short* __restrict__ h16, const float* __restrict__ comp_l,
    const int* __restrict__ row_start, const int* __restrict__ edge_p,
    unsigned short* __restrict__ Gf, int c0, int nc) {
    __shared__ float cs[NUM_RELS * NUM_BASES];
    if (threadIdx.x < NUM_RELS * NUM_BASES) cs[threadIdx.x] = comp_l[threadIdx.x];
    __syncthreads();
    int wave = threadIdx.x >> 6, lane = threadIdx.x & 63;
    int n = c0 + blockIdx.x * 4 + wave;
    if (n >= c0 + nc) return;
    int e0 = row_start[n], e1 = row_start[n + 1];
    float2 acc[NUM_BASES];
#pragma unroll
    for (int b = 0; b < NUM_BASES; b++) acc[b] = make_float2(0.f, 0.f);
    int e = e0;
    // 4-deep unroll: issue 4 independent row-gathers before consuming any
    for (; e + 4 <= e1; e += 4) {
        int p0 = edge_p[e], p1 = edge_p[e + 1], p2 = edge_p[e + 2], p3 = edge_p[e + 3];
        unsigned u0 = ((const unsigned*)(h16 + (size_t)(p0 >> 5) * HID))[lane];
        unsigned u1 = ((const unsigned*)(h16 + (size_t)(p1 >> 5) * HID))[lane];
        unsigned u2 = ((const unsigned*)(h16 + (size_t)(p2 >> 5) * HID))[lane];
        unsigned u3 = ((const unsigned*)(h16 + (size_t)(p3 >> 5) * HID))[lane];
        const float* c0p = &cs[(p0 & 31) * NUM_BASES];
        const float* c1p = &cs[(p1 & 31) * NUM_BASES];
        const float* c2p = &cs[(p2 & 31) * NUM_BASES];
        const float* c3p = &cs[(p3 & 31) * NUM_BASES];
        float2 v0 = __half22float2(__builtin_bit_cast(__half2, u0));
        float2 v1 = __half22float2(__builtin_bit_cast(__half2, u1));
        float2 v2 = __half22float2(__builtin_bit_cast(__half2, u2));
        float2 v3 = __half22float2(__builtin_bit_cast(__half2, u3));
#pragma unroll
        for (int b = 0; b < NUM_BASES; b++) {
            acc[b].x = fmaf(c0p[b], v0.x, acc[b].x);
            acc[b].y = fmaf(c0p[b], v0.y, acc[b].y);
            acc[b].x = fmaf(c1p[b], v1.x, acc[b].x);
            acc[b].y = fmaf(c1p[b], v1.y, acc[b].y);
            acc[b].x = fmaf(c2p[b], v2.x, acc[b].x);
            acc[b].y = fmaf(c2p[b], v2.y, acc[b].y);
            acc[b].x = fmaf(c3p[b], v3.x, acc[b].x);
            acc[b].y = fmaf(c3p[b], v3.y, acc[b].y);
        }
    }
    for (; e < e1; e++) {
        int se = edge_p[e];
        const float* c = &cs[(se & 31) * NUM_BASES];
        unsigned u = ((const unsigned*)(h16 + (size_t)(se >> 5) * HID))[lane];
        float2 v = __half22float2(__builtin_bit_cast(__half2, u));
#pragma unroll
        for (int b = 0; b < NUM_BASES; b++) {
            acc[b].x = fmaf(c[b], v.x, acc[b].x);
            acc[b].y = fmaf(c[b], v.y, acc[b].y);
        }
    }
    size_t base = (size_t)(n - c0) * 1024 + 2 * lane;
#pragma unroll
    for (int b = 0; b < NUM_BASES; b++) {
        __half2 g2 = __floats2half2_rn(acc[b].x, acc[b].y);
        *(unsigned*)&Gf[base + b * 128] = __builtin_bit_cast(unsigned, g2);
    }
}

// ---------------- B fragment table: f16 hi + f16 (lo*4096) of [Vl ; Wl], MFMA fragment order ----------------
// entry (l, s, t, lane): 16 ushort = hi[8], lo[8];
// element j: B[k = s*32 + (lane>>4)*8 + j][col = t*16 + (lane&15)] of layer l.
__global__ void k_bfrag(const float* __restrict__ V, const float* __restrict__ W_loop,
                        unsigned short* __restrict__ Bf) {
    int idx = blockIdx.x * 256 + threadIdx.x;
    if (idx >= NUM_LAYERS * 36 * 8 * 64) return;
    int lane = idx & 63;
    int t = (idx >> 6) & 7;
    int s = (idx >> 9) % 36;
    int l = (idx >> 9) / 36;
    int col = t * 16 + (lane & 15);
    int kbase = s * 32 + (lane >> 4) * 8;
    unsigned short* o = Bf + (size_t)idx * 16;
#pragma unroll
    for (int j = 0; j < 8; j++) {
        int k = kbase + j;
        float f = (k < 1024) ? V[((size_t)l * 1024 + k) * HID + col]
                             : W_loop[((size_t)l * HID + (k - 1024)) * HID + col];
        __half hh = __float2half(f);
        float res = (f - __half2float(hh)) * 4096.f;
        __half hl = __float2half(res);
        o[j] = __builtin_bit_cast(unsigned short, hh);
        o[8 + j] = __builtin_bit_cast(unsigned short, hl);
    }
}

// ---------------- f16 MFMA GEMM (BM=32, BK=64), global_load_lds dbuf A staging ----------------
// out = relu([G | h] @ [Vl ; Wl] + bl); also fp16 copy.  M=nc, K=1152, N=128.
// A is fp16 (G / h16 direct); B = Bh + Bl/4096 via dual accumulators (2 MFMA/tile).
// Block = 32 rows x 128 cols, 4 waves col-split (wave w -> t=2w,2w+1).
// LDS: 2 bufs x 4 frags (2 k-subtiles x 2 rowgroups) x 1KB = 8KB, lane-linear.
__global__ void __launch_bounds__(256) k_gemm7(
    const unsigned short* __restrict__ Gf, const unsigned short* __restrict__ h16,
    const unsigned short* __restrict__ Bf, const float* __restrict__ bl,
    float* __restrict__ out, unsigned short* __restrict__ out16, int c0, int nc) {
    __shared__ unsigned short smem[2][4][512];  // [buf][frag][1KB]
    int lane = threadIdx.x & 63;
    int w = threadIdx.x >> 6;
    int rit = lane & 15, kg = lane >> 4;
    int r0 = blockIdx.x * 32;
    // staging role: wave w stages frag F = (st_s*2 + st_i), st_i = w&1 rowgroup, st_s = w>>1 k-subtile
    int st_i = w & 1, st_s = w >> 1;
    int st_row = r0 + st_i * 16 + rit; if (st_row >= nc) st_row = nc - 1;
    const unsigned short* gsrc = Gf + (size_t)st_row * 1024 + st_s * 32 + kg * 8;
    const f16x8* bb = (const f16x8*)Bf + ((size_t)(2 * w) * 64 + lane) * 2;
    f32x4 ah00 = {}, ah01 = {}, ah10 = {}, ah11 = {};
    f32x4 al00 = {}, al01 = {}, al10 = {}, al11 = {};

#define STAGE(BUF, STEP) \
        gld_lds16(&smem[BUF][st_s * 2 + st_i][0], gsrc + (STEP) * 64);
#define CSTEP(BUF, STEP) _Pragma("unroll")                                   \
    for (int s = 0; s < 2; s++) {                                            \
        const f16x8* bp = bb + (size_t)((STEP) * 2 + s) * 1024;              \
        f16x8 bh0 = bp[0], bq0 = bp[1], bh1 = bp[128], bq1 = bp[129];        \
        f16x8 a0 = *(const f16x8*)&smem[BUF][s * 2 + 0][lane * 8];           \
        f16x8 a1 = *(const f16x8*)&smem[BUF][s * 2 + 1][lane * 8];           \
        ah00 = __builtin_amdgcn_mfma_f32_16x16x32_f16(a0, bh0, ah00, 0, 0, 0); \
        al00 = __builtin_amdgcn_mfma_f32_16x16x32_f16(a0, bq0, al00, 0, 0, 0); \
        ah01 = __builtin_amdgcn_mfma_f32_16x16x32_f16(a0, bh1, ah01, 0, 0, 0); \
        al01 = __builtin_amdgcn_mfma_f32_16x16x32_f16(a0, bq1, al01, 0, 0, 0); \
        ah10 = __builtin_amdgcn_mfma_f32_16x16x32_f16(a1, bh0, ah10, 0, 0, 0); \
        al10 = __builtin_amdgcn_mfma_f32_16x16x32_f16(a1, bq0, al10, 0, 0, 0); \
        ah11 = __builtin_amdgcn_mfma_f32_16x16x32_f16(a1, bh1, ah11, 0, 0, 0); \
        al11 = __builtin_amdgcn_mfma_f32_16x16x32_f16(a1, bq1, al11, 0, 0, 0); \
    }

    STAGE(0, 0);
    for (int t = 0; t < 16; t++) {
        __syncthreads();
        if (t < 15) STAGE((t + 1) & 1, t + 1);
        CSTEP(t & 1, t);
    }
    // K tail 1024..1151 (self-loop) straight from fp16 h16
    {
        int rT0 = r0 + rit;      if (rT0 >= nc) rT0 = nc - 1;
        int rT1 = r0 + 16 + rit; if (rT1 >= nc) rT1 = nc - 1;
        const unsigned short* hp0 = h16 + (size_t)(c0 + rT0) * HID + kg * 8;
        const unsigned short* hp1 = h16 + (size_t)(c0 + rT1) * HID + kg * 8;
#pragma unroll
        for (int s = 32; s < 36; s++) {
            int o = (s - 32) * 32;
            f16x8 a0 = *(const f16x8*)(hp0 + o);
            f16x8 a1 = *(const f16x8*)(hp1 + o);
            const f16x8* bp = bb + (size_t)s * 1024;
            f16x8 bh0 = bp[0], bq0 = bp[1], bh1 = bp[128], bq1 = bp[129];
            ah00 = __builtin_amdgcn_mfma_f32_16x16x32_f16(a0, bh0, ah00, 0, 0, 0);
            al00 = __builtin_amdgcn_mfma_f32_16x16x32_f16(a0, bq0, al00, 0, 0, 0);
            ah01 = __builtin_amdgcn_mfma_f32_16x16x32_f16(a0, bh1, ah01, 0, 0, 0);
            al01 = __builtin_amdgcn_mfma_f32_16x16x32_f16(a0, bq1, al01, 0, 0, 0);
            ah10 = __builtin_amdgcn_mfma_f32_16x16x32_f16(a1, bh0, ah10, 0, 0, 0);
            al10 = __builtin_amdgcn_mfma_f32_16x16x32_f16(a1, bq0, al10, 0, 0, 0);
            ah11 = __builtin_amdgcn_mfma_f32_16x16x32_f16(a1, bh1, ah11, 0, 0, 0);
            al11 = __builtin_amdgcn_mfma_f32_16x16x32_f16(a1, bq1, al11, 0, 0, 0);
        }
    }
#undef STAGE
#undef CSTEP
    const float INV = 1.f / 4096.f;
    int col0 = 2 * w * 16 + rit;
    float b0 = bl[col0], b1 = bl[col0 + 16];
    int rq = r0 + kg * 4;
#pragma unroll
    for (int q = 0; q < 4; q++) {
        int rA = rq + q;
        if (rA < nc) {
            float v0 = fmaxf(fmaf(al00[q], INV, ah00[q]) + b0, 0.f);
            float v1 = fmaxf(fmaf(al01[q], INV, ah01[q]) + b1, 0.f);
            size_t o = (size_t)(c0 + rA) * HID;
            out[o + col0] = v0; out[o + col0 + 16] = v1;
            out16[o + col0] = __builtin_bit_cast(unsigned short, __float2half(v0));
            out16[o + col0 + 16] = __builtin_bit_cast(unsigned short, __float2half(v1));
        }
        int rB = rA + 16;
        if (rB < nc) {
            float v0 = fmaxf(fmaf(al10[q], INV, ah10[q]) + b0, 0.f);
            float v1 = fmaxf(fmaf(al11[q], INV, ah11[q]) + b1, 0.f);
            size_t o = (size_t)(c0 + rB) * HID;
            out[o + col0] = v0; out[o + col0 + 16] = v1;
            out16[o + col0] = __builtin_bit_cast(unsigned short, __float2half(v0));
            out16[o + col0 + 16] = __builtin_bit_cast(unsigned short, __float2half(v1));
        }
    }
}

// ---------------- attention scalar score per node (16 nodes/block) ----------------
__global__ void __launch_bounds__(128) k_score(
    const float* __restrict__ h, const float* __restrict__ er,
    const float* __restrict__ Wa, const float* __restrict__ ba,
    const float* __restrict__ wsc, const float* __restrict__ bsc,
    float* __restrict__ a) {
    int n0 = blockIdx.x * 16;
    int j = threadIdx.x;
    int u = j >> 3, q = j & 7;
    __shared__ float xT[160][16];
    {
        const float4* h4 = (const float4*)(h + (size_t)(n0 + u) * HID);
#pragma unroll
        for (int k = 0; k < 4; k++) {
            float4 v = h4[q + 8 * k];
            xT[32 * k + 4 * q + 0][u] = v.x; xT[32 * k + 4 * q + 1][u] = v.y;
            xT[32 * k + 4 * q + 2][u] = v.z; xT[32 * k + 4 * q + 3][u] = v.w;
        }
        float4 e4 = ((const float4*)(er + (size_t)(n0 + u) * REL_DIM))[q];
        xT[128 + 4 * q + 0][u] = e4.x; xT[128 + 4 * q + 1][u] = e4.y;
        xT[128 + 4 * q + 2][u] = e4.z; xT[128 + 4 * q + 3][u] = e4.w;
    }
    __syncthreads();
    float bj = ba[j];
    float acc[16];
#pragma unroll
    for (int k = 0; k < 16; k++) acc[k] = bj;
    for (int d = 0; d < 160; d++) {
        float w = Wa[d * HID + j];
        float4 x0 = *(const float4*)&xT[d][0];
        float4 x1 = *(const float4*)&xT[d][4];
        float4 x2 = *(const float4*)&xT[d][8];
        float4 x3 = *(const float4*)&xT[d][12];
        acc[0]  = fmaf(x0.x, w, acc[0]);  acc[1]  = fmaf(x0.y, w, acc[1]);
        acc[2]  = fmaf(x0.z, w, acc[2]);  acc[3]  = fmaf(x0.w, w, acc[3]);
        acc[4]  = fmaf(x1.x, w, acc[4]);  acc[5]  = fmaf(x1.y, w, acc[5]);
        acc[6]  = fmaf(x1.z, w, acc[6]);  acc[7]  = fmaf(x1.w, w, acc[7]);
        acc[8]  = fmaf(x2.x, w, acc[8]);  acc[9]  = fmaf(x2.y, w, acc[9]);
        acc[10] = fmaf(x2.z, w, acc[10]); acc[11] = fmaf(x2.w, w, acc[11]);
        acc[12] = fmaf(x3.x, w, acc[12]); acc[13] = fmaf(x3.y, w, acc[13]);
        acc[14] = fmaf(x3.z, w, acc[14]); acc[15] = fmaf(x3.w, w, acc[15]);
    }
    __shared__ float red[16][128];
    float wj = wsc[j];
#pragma unroll
    for (int k = 0; k < 16; k++) red[k][j] = tanhf(acc[k]) * wj;
    __syncthreads();
    for (int s = 64; s > 0; s >>= 1) {
        if (j < s) {
#pragma unroll
            for (int k = 0; k < 16; k++) red[k][j] += red[k][j + s];
        }
        __syncthreads();
    }
    if (j < 16) a[n0 + j] = red[j][0] + bsc[0];
}

// ---------------- graph boundaries (graph_id is sorted) ----------------
__global__ void k_starts(const int* __restrict__ gid, int* __restrict__ starts) {
    int g = threadIdx.x;  // 0..255
    int lo = 0, hi = N_NODES;
    while (lo < hi) {
        int mid = (lo + hi) >> 1;
        if (gid[mid] < g) lo = mid + 1; else hi = mid;
    }
    starts[g] = lo;
    if (g == 0) starts[NUM_GRAPHS] = N_NODES;
}

// ---------------- segment softmax pooling + final dot ----------------
__global__ void __launch_bounds__(128) k_pool(
    const float* __restrict__ h, const float* __restrict__ a,
    const int* __restrict__ starts, const float* __restrict__ wout,
    const float* __restrict__ bout, float* __restrict__ out) {
    int g = blockIdx.x, j = threadIdx.x;
    int s0 = starts[g], s1 = starts[g + 1];
    __shared__ float red[128];
    __shared__ float exb[128];
    if (s1 <= s0) { if (j == 0) out[g] = bout[0]; return; }
    float m = -3.4e38f;
    for (int i = s0 + j; i < s1; i += 128) m = fmaxf(m, a[i]);
    red[j] = m; __syncthreads();
    for (int s = 64; s > 0; s >>= 1) {
        if (j < s) red[j] = fmaxf(red[j], red[j + s]);
        __syncthreads();
    }
    m = red[0]; __syncthreads();
    float zj = 0.f, ss = 0.f;
    for (int base = s0; base < s1; base += 128) {
        int cnt = min(128, s1 - base);
        float ev = 0.f;
        if (j < cnt) ev = expf(a[base + j] - m);
        exb[j] = ev;
        ss += ev;
        __syncthreads();
        for (int k = 0; k < cnt; k++)
            zj = fmaf(exb[k], h[(size_t)(base + k) * HID + j], zj);
        __syncthreads();
    }
    red[j] = ss; __syncthreads();
    for (int s = 64; s > 0; s >>= 1) {
        if (j < s) red[j] += red[j + s];
        __syncthreads();
    }
    ss = red[0]; __syncthreads();
    red[j] = (zj / ss) * wout[j]; __syncthreads();
    for (int s = 64; s > 0; s >>= 1) {
        if (j < s) red[j] += red[j + s];
        __syncthreads();
    }
    if (j == 0) out[g] = red[0] + bout[0];
}

extern "C" void kernel_launch(void* const* d_in, const int* in_sizes, int n_in,
                              void* d_out, int out_size, void* d_ws, size_t ws_size,
                              hipStream_t stream) {
    const float* feat    = (const float*)d_in[0];
    const int*   qrel    = (const int*)d_in[1];
    const int*   src     = (const int*)d_in[2];
    const int*   dst     = (const int*)d_in[3];
    const int*   ety     = (const int*)d_in[4];
    const int*   gid     = (const int*)d_in[5];
    const float* rel_emb = (const float*)d_in[6];
    const float* W_in    = (const float*)d_in[7];
    const float* b_in    = (const float*)d_in[8];
    const float* V       = (const float*)d_in[9];
    const float* comp    = (const float*)d_in[10];
    const float* W_loop  = (const float*)d_in[11];
    const float* b_loop  = (const float*)d_in[12];
    const float* W_attn  = (const float*)d_in[13];
    const float* b_attn  = (const float*)d_in[14];
    const float* w_sc    = (const float*)d_in[15];
    const float* b_sc    = (const float*)d_in[16];
    const float* w_out   = (const float*)d_in[17];
    const float* b_out   = (const float*)d_in[18];
    float* out = (float*)d_out;

    float* ws = (float*)d_ws;
    float* h0 = ws;                                       // 6.4M floats
    float* h1 = h0 + (size_t)N_NODES * HID;               // 6.4M
    unsigned short* h16a = (unsigned short*)(h1 + (size_t)N_NODES * HID);  // 6.4M ushort
    unsigned short* h16b = h16a + (size_t)N_NODES * HID;                   // 6.4M ushort
    float* er = (float*)(h16b + (size_t)N_NODES * HID);   // 1.6M
    float* af = er + (size_t)N_NODES * REL_DIM;           // 50000
    int* starts    = (int*)(af + N_NODES);                // 260
    int* deg       = starts + 260;                        // 50000
    int* row_start = deg + 50000;                         // 50004
    int* cursor    = row_start + 50004;                   // 50000
    int* bsum      = cursor + 50000;                      // 256
    int* boff      = bsum + 256;                          // 256
    int* edge_p    = boff + 256;                          // 800000 packed ints
    unsigned short* Bf = (unsigned short*)(edge_p + 800000);  // 2*36*8*64*16 ushort
    const size_t BF_USHORT = (size_t)NUM_LAYERS * 36 * 8 * 64 * 16;
    unsigned short* Gf = Bf + BF_USHORT;

    size_t used_floats = (size_t)((float*)Gf - ws);
    size_t total_floats = ws_size / sizeof(float);
    size_t avail = (total_floats > used_floats) ? (total_floats - used_floats) : 0;
    long long NC = (long long)(avail / 512);   // 1024 fp16 per row = 512 floats
    NC = (NC / 64) * 64;
    if (NC > 50048) NC = 50048;
    if (NC < 64) NC = 64;

    // --- preprocessing ---
    k_zero<<<(12500 + 255) / 256, 256, 0, stream>>>((float*)deg, 12500);
    k_hist<<<(N_EDGES + 255) / 256, 256, 0, stream>>>(dst, deg);
    k_scan_a<<<SCAN_BLKS, 256, 0, stream>>>(deg, row_start, bsum);
    k_scan_b<<<1, 256, 0, stream>>>(bsum, boff);
    k_scan_c<<<SCAN_BLKS, 256, 0, stream>>>(row_start, boff, cursor);
    k_scatter<<<(N_EDGES + 255) / 256, 256, 0, stream>>>(src, dst, ety, cursor, edge_p);
    k_bfrag<<<(NUM_LAYERS * 36 * 8 * 64 + 255) / 256, 256, 0, stream>>>(V, W_loop, Bf);
    k_input<<<N_NODES / 16, 128, 0, stream>>>(feat, qrel, rel_emb, W_in, b_in, h0, h16a, er);

    float* hcur = h0;
    float* hnext = h1;
    unsigned short* h16cur = h16a;
    unsigned short* h16next = h16b;
    for (int l = 0; l < NUM_LAYERS; l++) {
        const float* comp_l = comp + (size_t)l * NUM_RELS * NUM_BASES;
        const unsigned short* Bfl = Bf + (size_t)l * 36 * 8 * 64 * 16;
        const float* bl = b_loop + (size_t)l * HID;
        for (int c0 = 0; c0 < N_NODES; c0 += (int)NC) {
            int nc = (int)((N_NODES - c0 < NC) ? (N_NODES - c0) : NC);
            k_mix2<<<(nc + 3) / 4, 256, 0, stream>>>(h16cur, comp_l, row_start, edge_p,
                                                     Gf, c0, nc);
            k_gemm7<<<(nc + 31) / 32, 256, 0, stream>>>(Gf, h16cur, Bfl, bl,
                                                        hnext, h16next, c0, nc);
        }
        float* tmp = hcur; hcur = hnext; hnext = tmp;
        unsigned short* tmp16 = h16cur; h16cur = h16next; h16next = tmp16;
    }

    k_score<<<N_NODES / 16, 128, 0, stream>>>(hcur, er, W_attn, b_attn, w_sc, b_sc, af);
    k_starts<<<1, 256, 0, stream>>>(gid, starts);
    k_pool<<<NUM_GRAPHS, 128, 0, stream>>>(hcur, af, starts, w_out, b_out, out);
}

// Round 13
// 412.107 us; speedup vs baseline: 1.5328x; 1.0128x over previous
//
#include <hip/hip_runtime.h>
#include <hip/hip_fp16.h>

#define N_NODES   50000
#define N_EDGES   800000
#define NUM_GRAPHS 256
#define IN_FEAT   64
#define REL_DIM   32
#define HID       128
#define NUM_RELS  32
#define NUM_BASES 8
#define NUM_LAYERS 2

#define SCAN_BLKS ((N_NODES + 255) / 256)   // 196

typedef __attribute__((ext_vector_type(8))) _Float16 f16x8;
typedef __attribute__((ext_vector_type(4))) float f32x4;

// async 16B global -> LDS (wave-uniform LDS base + lane*16; per-lane global src)
__device__ __forceinline__ void gld_lds16(void* lds, const void* g) {
    __builtin_amdgcn_global_load_lds(
        (const __attribute__((address_space(1))) unsigned int*)g,
        (__attribute__((address_space(3))) unsigned int*)lds, 16, 0, 0);
}

// ---------------- zero (float4 granularity) ----------------
__global__ void k_zero(float* __restrict__ p, int n4) {
    int i = blockIdx.x * 256 + threadIdx.x;
    if (i < n4) ((float4*)p)[i] = make_float4(0.f, 0.f, 0.f, 0.f);
}

// ---------------- CSR build: histogram, 3-phase scan, scatter ----------------
__global__ void k_hist(const int* __restrict__ dst, int* __restrict__ deg) {
    int e = blockIdx.x * 256 + threadIdx.x;
    if (e < N_EDGES) atomicAdd(&deg[dst[e]], 1);
}

__global__ void __launch_bounds__(256) k_scan_a(
    const int* __restrict__ deg, int* __restrict__ row_start, int* __restrict__ bsum) {
    __shared__ int s[256];
    int t = threadIdx.x;
    int idx = blockIdx.x * 256 + t;
    int v = (idx < N_NODES) ? deg[idx] : 0;
    s[t] = v;
    __syncthreads();
    for (int off = 1; off < 256; off <<= 1) {
        int u = (t >= off) ? s[t - off] : 0;
        __syncthreads();
        s[t] += u;
        __syncthreads();
    }
    if (idx < N_NODES) row_start[idx] = s[t] - v;   // local exclusive
    if (t == 255) bsum[blockIdx.x] = s[255];
}

__global__ void __launch_bounds__(256) k_scan_b(int* __restrict__ bsum,
                                                int* __restrict__ boff) {
    __shared__ int s[256];
    int t = threadIdx.x;
    int v = (t < SCAN_BLKS) ? bsum[t] : 0;
    s[t] = v;
    __syncthreads();
    for (int off = 1; off < 256; off <<= 1) {
        int u = (t >= off) ? s[t - off] : 0;
        __syncthreads();
        s[t] += u;
        __syncthreads();
    }
    if (t < SCAN_BLKS) boff[t] = s[t] - v;          // exclusive
}

__global__ void __launch_bounds__(256) k_scan_c(
    int* __restrict__ row_start, const int* __restrict__ boff,
    int* __restrict__ cursor) {
    int idx = blockIdx.x * 256 + threadIdx.x;
    if (idx < N_NODES) {
        int r = row_start[idx] + boff[blockIdx.x];
        row_start[idx] = r;
        cursor[idx] = r;
    }
    if (idx == 0) row_start[N_NODES] = N_EDGES;
}

// packed payload: (src << 5) | ety   (src < 2^17, ety < 32)
__global__ void k_scatter(const int* __restrict__ src, const int* __restrict__ dst,
                          const int* __restrict__ ety, int* __restrict__ cursor,
                          int* __restrict__ edge_p) {
    int e = blockIdx.x * 256 + threadIdx.x;
    if (e >= N_EDGES) return;
    int d = dst[e];
    int pos = atomicAdd(&cursor[d], 1);
    edge_p[pos] = (src[e] << 5) | ety[e];
}

// ---------------- input projection (16 nodes/block): h = relu([feat, er] @ W_in + b_in) ----------------
__global__ void __launch_bounds__(128) k_input(
    const float* __restrict__ feat, const int* __restrict__ qrel,
    const float* __restrict__ rel_emb, const float* __restrict__ Wi,
    const float* __restrict__ bi, float* __restrict__ h,
    unsigned short* __restrict__ h16, float* __restrict__ er) {
    int n0 = blockIdx.x * 16;
    int j = threadIdx.x;
    int u = j >> 3, q = j & 7;
    __shared__ float xT[96][16];
    {
        const float4* f4 = (const float4*)(feat + (size_t)(n0 + u) * IN_FEAT);
        float4 a = f4[q], b = f4[q + 8];
        xT[4 * q + 0][u] = a.x; xT[4 * q + 1][u] = a.y;
        xT[4 * q + 2][u] = a.z; xT[4 * q + 3][u] = a.w;
        xT[32 + 4 * q + 0][u] = b.x; xT[32 + 4 * q + 1][u] = b.y;
        xT[32 + 4 * q + 2][u] = b.z; xT[32 + 4 * q + 3][u] = b.w;
        int qr = qrel[n0 + u];
        float4 e4 = ((const float4*)(rel_emb + (size_t)qr * REL_DIM))[q];
        xT[64 + 4 * q + 0][u] = e4.x; xT[64 + 4 * q + 1][u] = e4.y;
        xT[64 + 4 * q + 2][u] = e4.z; xT[64 + 4 * q + 3][u] = e4.w;
        ((float4*)(er + (size_t)(n0 + u) * REL_DIM))[q] = e4;
    }
    __syncthreads();
    float bj = bi[j];
    float acc[16];
#pragma unroll
    for (int k = 0; k < 16; k++) acc[k] = bj;
    for (int d = 0; d < 96; d++) {
        float w = Wi[d * HID + j];
        float4 x0 = *(const float4*)&xT[d][0];
        float4 x1 = *(const float4*)&xT[d][4];
        float4 x2 = *(const float4*)&xT[d][8];
        float4 x3 = *(const float4*)&xT[d][12];
        acc[0]  = fmaf(x0.x, w, acc[0]);  acc[1]  = fmaf(x0.y, w, acc[1]);
        acc[2]  = fmaf(x0.z, w, acc[2]);  acc[3]  = fmaf(x0.w, w, acc[3]);
        acc[4]  = fmaf(x1.x, w, acc[4]);  acc[5]  = fmaf(x1.y, w, acc[5]);
        acc[6]  = fmaf(x1.z, w, acc[6]);  acc[7]  = fmaf(x1.w, w, acc[7]);
        acc[8]  = fmaf(x2.x, w, acc[8]);  acc[9]  = fmaf(x2.y, w, acc[9]);
        acc[10] = fmaf(x2.z, w, acc[10]); acc[11] = fmaf(x2.w, w, acc[11]);
        acc[12] = fmaf(x3.x, w, acc[12]); acc[13] = fmaf(x3.y, w, acc[13]);
        acc[14] = fmaf(x3.z, w, acc[14]); acc[15] = fmaf(x3.w, w, acc[15]);
    }
#pragma unroll
    for (int k = 0; k < 16; k++) {
        float v = fmaxf(acc[k], 0.f);
        h[(size_t)(n0 + k) * HID + j] = v;
        __half hv = __float2half(v);
        h16[(size_t)(n0 + k) * HID + j] = __builtin_bit_cast(unsigned short, hv);
    }
}

// ---------------- per-dst basis-weighted gather (fp16 h), 4-deep MLP, fp16 G output ----------------
// Gf[n-c0][b*128+d] = fp16( sum_e c[ety,b]*h16[src,d] )
__global__ void __launch_bounds__(256) k_mix2(
    const unsigned short* __restrict__ h16, const float* __restrict__ comp_l,
    const int* __restrict__ row_start, const int* __restrict__ edge_p,
    unsigned short* __restrict__ Gf, int c0, int nc) {
    __shared__ float cs[NUM_RELS * NUM_BASES];
    if (threadIdx.x < NUM_RELS * NUM_BASES) cs[threadIdx.x] = comp_l[threadIdx.x];
    __syncthreads();
    int wave = threadIdx.x >> 6, lane = threadIdx.x & 63;
    int n = c0 + blockIdx.x * 4 + wave;
    if (n >= c0 + nc) return;
    int e0 = row_start[n], e1 = row_start[n + 1];
    float2 acc[NUM_BASES];
#pragma unroll
    for (int b = 0; b < NUM_BASES; b++) acc[b] = make_float2(0.f, 0.f);
    int e = e0;
    for (; e + 4 <= e1; e += 4) {
        int p0 = edge_p[e], p1 = edge_p[e + 1], p2 = edge_p[e + 2], p3 = edge_p[e + 3];
        unsigned u0 = ((const unsigned*)(h16 + (size_t)(p0 >> 5) * HID))[lane];
        unsigned u1 = ((const unsigned*)(h16 + (size_t)(p1 >> 5) * HID))[lane];
        unsigned u2 = ((const unsigned*)(h16 + (size_t)(p2 >> 5) * HID))[lane];
        unsigned u3 = ((const unsigned*)(h16 + (size_t)(p3 >> 5) * HID))[lane];
        const float* c0p = &cs[(p0 & 31) * NUM_BASES];
        const float* c1p = &cs[(p1 & 31) * NUM_BASES];
        const float* c2p = &cs[(p2 & 31) * NUM_BASES];
        const float* c3p = &cs[(p3 & 31) * NUM_BASES];
        float2 v0 = __half22float2(__builtin_bit_cast(__half2, u0));
        float2 v1 = __half22float2(__builtin_bit_cast(__half2, u1));
        float2 v2 = __half22float2(__builtin_bit_cast(__half2, u2));
        float2 v3 = __half22float2(__builtin_bit_cast(__half2, u3));
#pragma unroll
        for (int b = 0; b < NUM_BASES; b++) {
            acc[b].x = fmaf(c0p[b], v0.x, acc[b].x);
            acc[b].y = fmaf(c0p[b], v0.y, acc[b].y);
            acc[b].x = fmaf(c1p[b], v1.x, acc[b].x);
            acc[b].y = fmaf(c1p[b], v1.y, acc[b].y);
            acc[b].x = fmaf(c2p[b], v2.x, acc[b].x);
            acc[b].y = fmaf(c2p[b], v2.y, acc[b].y);
            acc[b].x = fmaf(c3p[b], v3.x, acc[b].x);
            acc[b].y = fmaf(c3p[b], v3.y, acc[b].y);
        }
    }
    for (; e < e1; e++) {
        int se = edge_p[e];
        const float* c = &cs[(se & 31) * NUM_BASES];
        unsigned u = ((const unsigned*)(h16 + (size_t)(se >> 5) * HID))[lane];
        float2 v = __half22float2(__builtin_bit_cast(__half2, u));
#pragma unroll
        for (int b = 0; b < NUM_BASES; b++) {
            acc[b].x = fmaf(c[b], v.x, acc[b].x);
            acc[b].y = fmaf(c[b], v.y, acc[b].y);
        }
    }
    size_t base = (size_t)(n - c0) * 1024 + 2 * lane;
#pragma unroll
    for (int b = 0; b < NUM_BASES; b++) {
        __half2 g2 = __floats2half2_rn(acc[b].x, acc[b].y);
        *(unsigned*)&Gf[base + b * 128] = __builtin_bit_cast(unsigned, g2);
    }
}

// ---------------- B fragment table: f16 hi + f16 (lo*4096) of [Vl ; Wl], MFMA fragment order ----------------
__global__ void k_bfrag(const float* __restrict__ V, const float* __restrict__ W_loop,
                        unsigned short* __restrict__ Bf) {
    int idx = blockIdx.x * 256 + threadIdx.x;
    if (idx >= NUM_LAYERS * 36 * 8 * 64) return;
    int lane = idx & 63;
    int t = (idx >> 6) & 7;
    int s = (idx >> 9) % 36;
    int l = (idx >> 9) / 36;
    int col = t * 16 + (lane & 15);
    int kbase = s * 32 + (lane >> 4) * 8;
    unsigned short* o = Bf + (size_t)idx * 16;
#pragma unroll
    for (int j = 0; j < 8; j++) {
        int k = kbase + j;
        float f = (k < 1024) ? V[((size_t)l * 1024 + k) * HID + col]
                             : W_loop[((size_t)l * HID + (k - 1024)) * HID + col];
        __half hh = __float2half(f);
        float res = (f - __half2float(hh)) * 4096.f;
        __half hl = __float2half(res);
        o[j] = __builtin_bit_cast(unsigned short, hh);
        o[8 + j] = __builtin_bit_cast(unsigned short, hl);
    }
}

// ---------------- f16 MFMA GEMM (BM=64, BK=128): 8 barriers, 64 MFMA/wave/barrier ----------------
// out = relu([G | h] @ [Vl ; Wl] + bl); also fp16 copy.  M=nc, K=1152, N=128.
// Block = 64 rows x 128 cols, 4 waves col-split (wave w -> t=2w,2w+1), 4 rowgroups.
// LDS: 2 bufs x 16 frags (4 k-subtiles x 4 rowgroups) x 1KB = 32KB, lane-linear.
// Wave w stages k-subtile w's 4 rowgroup frags each step (4 x gld_lds16).
__global__ void __launch_bounds__(256) k_gemm8(
    const unsigned short* __restrict__ Gf, const unsigned short* __restrict__ h16,
    const unsigned short* __restrict__ Bf, const float* __restrict__ bl,
    float* __restrict__ out, unsigned short* __restrict__ out16, int c0, int nc) {
    __shared__ unsigned short smem[2][16][512];  // [buf][frag][1KB] = 32KB
    int lane = threadIdx.x & 63;
    int w = threadIdx.x >> 6;
    int rit = lane & 15, kg = lane >> 4;
    int r0 = blockIdx.x * 64;
    // staging rows for the 4 rowgroups (this wave stages k-subtile s_local = w)
    int sr0 = r0 + 0 * 16 + rit; if (sr0 >= nc) sr0 = nc - 1;
    int sr1 = r0 + 1 * 16 + rit; if (sr1 >= nc) sr1 = nc - 1;
    int sr2 = r0 + 2 * 16 + rit; if (sr2 >= nc) sr2 = nc - 1;
    int sr3 = r0 + 3 * 16 + rit; if (sr3 >= nc) sr3 = nc - 1;
    int koff = w * 32 + kg * 8;
    const unsigned short* gs0 = Gf + (size_t)sr0 * 1024 + koff;
    const unsigned short* gs1 = Gf + (size_t)sr1 * 1024 + koff;
    const unsigned short* gs2 = Gf + (size_t)sr2 * 1024 + koff;
    const unsigned short* gs3 = Gf + (size_t)sr3 * 1024 + koff;
    const f16x8* bb = (const f16x8*)Bf + ((size_t)(2 * w) * 64 + lane) * 2;
    f32x4 accH[4][2] = {};
    f32x4 accL[4][2] = {};

#define STAGE(BUF, STEP) {                                        \
        gld_lds16(&smem[BUF][w * 4 + 0][0], gs0 + (STEP) * 128);  \
        gld_lds16(&smem[BUF][w * 4 + 1][0], gs1 + (STEP) * 128);  \
        gld_lds16(&smem[BUF][w * 4 + 2][0], gs2 + (STEP) * 128);  \
        gld_lds16(&smem[BUF][w * 4 + 3][0], gs3 + (STEP) * 128); }
#define CSTEP(BUF, STEP) _Pragma("unroll")                                   \
    for (int s = 0; s < 4; s++) {                                            \
        const f16x8* bp = bb + (size_t)((STEP) * 4 + s) * 1024;              \
        f16x8 bh0 = bp[0], bq0 = bp[1], bh1 = bp[128], bq1 = bp[129];        \
        _Pragma("unroll")                                                    \
        for (int i = 0; i < 4; i++) {                                        \
            f16x8 a = *(const f16x8*)&smem[BUF][s * 4 + i][lane * 8];        \
            accH[i][0] = __builtin_amdgcn_mfma_f32_16x16x32_f16(a, bh0, accH[i][0], 0, 0, 0); \
            accL[i][0] = __builtin_amdgcn_mfma_f32_16x16x32_f16(a, bq0, accL[i][0], 0, 0, 0); \
            accH[i][1] = __builtin_amdgcn_mfma_f32_16x16x32_f16(a, bh1, accH[i][1], 0, 0, 0); \
            accL[i][1] = __builtin_amdgcn_mfma_f32_16x16x32_f16(a, bq1, accL[i][1], 0, 0, 0); \
        }                                                                    \
    }

    STAGE(0, 0);
    for (int t = 0; t < 8; t++) {
        __syncthreads();
        if (t < 7) STAGE((t + 1) & 1, t + 1);
        CSTEP(t & 1, t);
    }
    // K tail 1024..1151 (self-loop) straight from fp16 h16
    {
        const unsigned short* hp0 = h16 + (size_t)(c0 + sr0) * HID + kg * 8;
        const unsigned short* hp1 = h16 + (size_t)(c0 + sr1) * HID + kg * 8;
        const unsigned short* hp2 = h16 + (size_t)(c0 + sr2) * HID + kg * 8;
        const unsigned short* hp3 = h16 + (size_t)(c0 + sr3) * HID + kg * 8;
#pragma unroll
        for (int s = 32; s < 36; s++) {
            int o = (s - 32) * 32;
            f16x8 a0 = *(const f16x8*)(hp0 + o);
            f16x8 a1 = *(const f16x8*)(hp1 + o);
            f16x8 a2 = *(const f16x8*)(hp2 + o);
            f16x8 a3 = *(const f16x8*)(hp3 + o);
            const f16x8* bp = bb + (size_t)s * 1024;
            f16x8 bh0 = bp[0], bq0 = bp[1], bh1 = bp[128], bq1 = bp[129];
            accH[0][0] = __builtin_amdgcn_mfma_f32_16x16x32_f16(a0, bh0, accH[0][0], 0, 0, 0);
            accL[0][0] = __builtin_amdgcn_mfma_f32_16x16x32_f16(a0, bq0, accL[0][0], 0, 0, 0);
            accH[0][1] = __builtin_amdgcn_mfma_f32_16x16x32_f16(a0, bh1, accH[0][1], 0, 0, 0);
            accL[0][1] = __builtin_amdgcn_mfma_f32_16x16x32_f16(a0, bq1, accL[0][1], 0, 0, 0);
            accH[1][0] = __builtin_amdgcn_mfma_f32_16x16x32_f16(a1, bh0, accH[1][0], 0, 0, 0);
            accL[1][0] = __builtin_amdgcn_mfma_f32_16x16x32_f16(a1, bq0, accL[1][0], 0, 0, 0);
            accH[1][1] = __builtin_amdgcn_mfma_f32_16x16x32_f16(a1, bh1, accH[1][1], 0, 0, 0);
            accL[1][1] = __builtin_amdgcn_mfma_f32_16x16x32_f16(a1, bq1, accL[1][1], 0, 0, 0);
            accH[2][0] = __builtin_amdgcn_mfma_f32_16x16x32_f16(a2, bh0, accH[2][0], 0, 0, 0);
            accL[2][0] = __builtin_amdgcn_mfma_f32_16x16x32_f16(a2, bq0, accL[2][0], 0, 0, 0);
            accH[2][1] = __builtin_amdgcn_mfma_f32_16x16x32_f16(a2, bh1, accH[2][1], 0, 0, 0);
            accL[2][1] = __builtin_amdgcn_mfma_f32_16x16x32_f16(a2, bq1, accL[2][1], 0, 0, 0);
            accH[3][0] = __builtin_amdgcn_mfma_f32_16x16x32_f16(a3, bh0, accH[3][0], 0, 0, 0);
            accL[3][0] = __builtin_amdgcn_mfma_f32_16x16x32_f16(a3, bq0, accL[3][0], 0, 0, 0);
            accH[3][1] = __builtin_amdgcn_mfma_f32_16x16x32_f16(a3, bh1, accH[3][1], 0, 0, 0);
            accL[3][1] = __builtin_amdgcn_mfma_f32_16x16x32_f16(a3, bq1, accL[3][1], 0, 0, 0);
        }
    }
#undef STAGE
#undef CSTEP
    const float INV = 1.f / 4096.f;
    int col0 = 2 * w * 16 + rit;
    float b0 = bl[col0], b1 = bl[col0 + 16];
#pragma unroll
    for (int i = 0; i < 4; i++) {
        int rq = r0 + i * 16 + kg * 4;
#pragma unroll
        for (int q = 0; q < 4; q++) {
            int row = rq + q;
            if (row < nc) {
                float v0 = fmaxf(fmaf(accL[i][0][q], INV, accH[i][0][q]) + b0, 0.f);
                float v1 = fmaxf(fmaf(accL[i][1][q], INV, accH[i][1][q]) + b1, 0.f);
                size_t o = (size_t)(c0 + row) * HID;
                out[o + col0] = v0; out[o + col0 + 16] = v1;
                out16[o + col0] = __builtin_bit_cast(unsigned short, __float2half(v0));
                out16[o + col0 + 16] = __builtin_bit_cast(unsigned short, __float2half(v1));
            }
        }
    }
}

// ---------------- attention scalar score per node (16 nodes/block) ----------------
__global__ void __launch_bounds__(128) k_score(
    const float* __restrict__ h, const float* __restrict__ er,
    const float* __restrict__ Wa, const float* __restrict__ ba,
    const float* __restrict__ wsc, const float* __restrict__ bsc,
    float* __restrict__ a) {
    int n0 = blockIdx.x * 16;
    int j = threadIdx.x;
    int u = j >> 3, q = j & 7;
    __shared__ float xT[160][16];
    {
        const float4* h4 = (const float4*)(h + (size_t)(n0 + u) * HID);
#pragma unroll
        for (int k = 0; k < 4; k++) {
            float4 v = h4[q + 8 * k];
            xT[32 * k + 4 * q + 0][u] = v.x; xT[32 * k + 4 * q + 1][u] = v.y;
            xT[32 * k + 4 * q + 2][u] = v.z; xT[32 * k + 4 * q + 3][u] = v.w;
        }
        float4 e4 = ((const float4*)(er + (size_t)(n0 + u) * REL_DIM))[q];
        xT[128 + 4 * q + 0][u] = e4.x; xT[128 + 4 * q + 1][u] = e4.y;
        xT[128 + 4 * q + 2][u] = e4.z; xT[128 + 4 * q + 3][u] = e4.w;
    }
    __syncthreads();
    float bj = ba[j];
    float acc[16];
#pragma unroll
    for (int k = 0; k < 16; k++) acc[k] = bj;
    for (int d = 0; d < 160; d++) {
        float w = Wa[d * HID + j];
        float4 x0 = *(const float4*)&xT[d][0];
        float4 x1 = *(const float4*)&xT[d][4];
        float4 x2 = *(const float4*)&xT[d][8];
        float4 x3 = *(const float4*)&xT[d][12];
        acc[0]  = fmaf(x0.x, w, acc[0]);  acc[1]  = fmaf(x0.y, w, acc[1]);
        acc[2]  = fmaf(x0.z, w, acc[2]);  acc[3]  = fmaf(x0.w, w, acc[3]);
        acc[4]  = fmaf(x1.x, w, acc[4]);  acc[5]  = fmaf(x1.y, w, acc[5]);
        acc[6]  = fmaf(x1.z, w, acc[6]);  acc[7]  = fmaf(x1.w, w, acc[7]);
        acc[8]  = fmaf(x2.x, w, acc[8]);  acc[9]  = fmaf(x2.y, w, acc[9]);
        acc[10] = fmaf(x2.z, w, acc[10]); acc[11] = fmaf(x2.w, w, acc[11]);
        acc[12] = fmaf(x3.x, w, acc[12]); acc[13] = fmaf(x3.y, w, acc[13]);
        acc[14] = fmaf(x3.z, w, acc[14]); acc[15] = fmaf(x3.w, w, acc[15]);
    }
    __shared__ float red[16][128];
    float wj = wsc[j];
#pragma unroll
    for (int k = 0; k < 16; k++) red[k][j] = tanhf(acc[k]) * wj;
    __syncthreads();
    for (int s = 64; s > 0; s >>= 1) {
        if (j < s) {
#pragma unroll
            for (int k = 0; k < 16; k++) red[k][j] += red[k][j + s];
        }
        __syncthreads();
    }
    if (j < 16) a[n0 + j] = red[j][0] + bsc[0];
}

// ---------------- graph boundaries (graph_id is sorted) ----------------
__global__ void k_starts(const int* __restrict__ gid, int* __restrict__ starts) {
    int g = threadIdx.x;  // 0..255
    int lo = 0, hi = N_NODES;
    while (lo < hi) {
        int mid = (lo + hi) >> 1;
        if (gid[mid] < g) lo = mid + 1; else hi = mid;
    }
    starts[g] = lo;
    if (g == 0) starts[NUM_GRAPHS] = N_NODES;
}

// ---------------- segment softmax pooling + final dot ----------------
__global__ void __launch_bounds__(128) k_pool(
    const float* __restrict__ h, const float* __restrict__ a,
    const int* __restrict__ starts, const float* __restrict__ wout,
    const float* __restrict__ bout, float* __restrict__ out) {
    int g = blockIdx.x, j = threadIdx.x;
    int s0 = starts[g], s1 = starts[g + 1];
    __shared__ float red[128];
    __shared__ float exb[128];
    if (s1 <= s0) { if (j == 0) out[g] = bout[0]; return; }
    float m = -3.4e38f;
    for (int i = s0 + j; i < s1; i += 128) m = fmaxf(m, a[i]);
    red[j] = m; __syncthreads();
    for (int s = 64; s > 0; s >>= 1) {
        if (j < s) red[j] = fmaxf(red[j], red[j + s]);
        __syncthreads();
    }
    m = red[0]; __syncthreads();
    float zj = 0.f, ss = 0.f;
    for (int base = s0; base < s1; base += 128) {
        int cnt = min(128, s1 - base);
        float ev = 0.f;
        if (j < cnt) ev = expf(a[base + j] - m);
        exb[j] = ev;
        ss += ev;
        __syncthreads();
        for (int k = 0; k < cnt; k++)
            zj = fmaf(exb[k], h[(size_t)(base + k) * HID + j], zj);
        __syncthreads();
    }
    red[j] = ss; __syncthreads();
    for (int s = 64; s > 0; s >>= 1) {
        if (j < s) red[j] += red[j + s];
        __syncthreads();
    }
    ss = red[0]; __syncthreads();
    red[j] = (zj / ss) * wout[j]; __syncthreads();
    for (int s = 64; s > 0; s >>= 1) {
        if (j < s) red[j] += red[j + s];
        __syncthreads();
    }
    if (j == 0) out[g] = red[0] + bout[0];
}

extern "C" void kernel_launch(void* const* d_in, const int* in_sizes, int n_in,
                              void* d_out, int out_size, void* d_ws, size_t ws_size,
                              hipStream_t stream) {
    const float* feat    = (const float*)d_in[0];
    const int*   qrel    = (const int*)d_in[1];
    const int*   src     = (const int*)d_in[2];
    const int*   dst     = (const int*)d_in[3];
    const int*   ety     = (const int*)d_in[4];
    const int*   gid     = (const int*)d_in[5];
    const float* rel_emb = (const float*)d_in[6];
    const float* W_in    = (const float*)d_in[7];
    const float* b_in    = (const float*)d_in[8];
    const float* V       = (const float*)d_in[9];
    const float* comp    = (const float*)d_in[10];
    const float* W_loop  = (const float*)d_in[11];
    const float* b_loop  = (const float*)d_in[12];
    const float* W_attn  = (const float*)d_in[13];
    const float* b_attn  = (const float*)d_in[14];
    const float* w_sc    = (const float*)d_in[15];
    const float* b_sc    = (const float*)d_in[16];
    const float* w_out   = (const float*)d_in[17];
    const float* b_out   = (const float*)d_in[18];
    float* out = (float*)d_out;

    float* ws = (float*)d_ws;
    float* h0 = ws;                                       // 6.4M floats
    float* h1 = h0 + (size_t)N_NODES * HID;               // 6.4M
    unsigned short* h16a = (unsigned short*)(h1 + (size_t)N_NODES * HID);  // 6.4M ushort
    unsigned short* h16b = h16a + (size_t)N_NODES * HID;                   // 6.4M ushort
    float* er = (float*)(h16b + (size_t)N_NODES * HID);   // 1.6M
    float* af = er + (size_t)N_NODES * REL_DIM;           // 50000
    int* starts    = (int*)(af + N_NODES);                // 260
    int* deg       = starts + 260;                        // 50000
    int* row_start = deg + 50000;                         // 50004
    int* cursor    = row_start + 50004;                   // 50000
    int* bsum      = cursor + 50000;                      // 256
    int* boff      = bsum + 256;                          // 256
    int* edge_p    = boff + 256;                          // 800000 packed ints
    unsigned short* Bf = (unsigned short*)(edge_p + 800000);  // 2*36*8*64*16 ushort
    const size_t BF_USHORT = (size_t)NUM_LAYERS * 36 * 8 * 64 * 16;
    unsigned short* Gf = Bf + BF_USHORT;

    size_t used_floats = (size_t)((float*)Gf - ws);
    size_t total_floats = ws_size / sizeof(float);
    size_t avail = (total_floats > used_floats) ? (total_floats - used_floats) : 0;
    long long NC = (long long)(avail / 512);   // 1024 fp16 per row = 512 floats
    NC = (NC / 64) * 64;
    if (NC > 50048) NC = 50048;
    if (NC < 64) NC = 64;

    // --- preprocessing ---
    k_zero<<<(12500 + 255) / 256, 256, 0, stream>>>((float*)deg, 12500);
    k_hist<<<(N_EDGES + 255) / 256, 256, 0, stream>>>(dst, deg);
    k_scan_a<<<SCAN_BLKS, 256, 0, stream>>>(deg, row_start, bsum);
    k_scan_b<<<1, 256, 0, stream>>>(bsum, boff);
    k_scan_c<<<SCAN_BLKS, 256, 0, stream>>>(row_start, boff, cursor);
    k_scatter<<<(N_EDGES + 255) / 256, 256, 0, stream>>>(src, dst, ety, cursor, edge_p);
    k_bfrag<<<(NUM_LAYERS * 36 * 8 * 64 + 255) / 256, 256, 0, stream>>>(V, W_loop, Bf);
    k_input<<<N_NODES / 16, 128, 0, stream>>>(feat, qrel, rel_emb, W_in, b_in, h0, h16a, er);

    float* hcur = h0;
    float* hnext = h1;
    unsigned short* h16cur = h16a;
    unsigned short* h16next = h16b;
    for (int l = 0; l < NUM_LAYERS; l++) {
        const float* comp_l = comp + (size_t)l * NUM_RELS * NUM_BASES;
        const unsigned short* Bfl = Bf + (size_t)l * 36 * 8 * 64 * 16;
        const float* bl = b_loop + (size_t)l * HID;
        for (int c0 = 0; c0 < N_NODES; c0 += (int)NC) {
            int nc = (int)((N_NODES - c0 < NC) ? (N_NODES - c0) : NC);
            k_mix2<<<(nc + 3) / 4, 256, 0, stream>>>(h16cur, comp_l, row_start, edge_p,
                                                     Gf, c0, nc);
            k_gemm8<<<(nc + 63) / 64, 256, 0, stream>>>(Gf, h16cur, Bfl, bl,
                                                        hnext, h16next, c0, nc);
        }
        float* tmp = hcur; hcur = hnext; hnext = tmp;
        unsigned short* tmp16 = h16cur; h16cur = h16next; h16next = tmp16;
    }

    k_score<<<N_NODES / 16, 128, 0, stream>>>(hcur, er, W_attn, b_attn, w_sc, b_sc, af);
    k_starts<<<1, 256, 0, stream>>>(gid, starts);
    k_pool<<<NUM_GRAPHS, 128, 0, stream>>>(hcur, af, starts, w_out, b_out, out);
}

// Round 14
// 399.797 us; speedup vs baseline: 1.5800x; 1.0308x over previous
//
#include <hip/hip_runtime.h>
#include <hip/hip_fp16.h>

#define N_NODES   50000
#define N_EDGES   800000
#define NUM_GRAPHS 256
#define IN_FEAT   64
#define REL_DIM   32
#define HID       128
#define NUM_RELS  32
#define NUM_BASES 8
#define NUM_LAYERS 2

#define SCAN_BLKS ((N_NODES + 255) / 256)   // 196

typedef __attribute__((ext_vector_type(8))) _Float16 f16x8;
typedef __attribute__((ext_vector_type(4))) float f32x4;

// async 16B global -> LDS (wave-uniform LDS base + lane*16; per-lane global src)
__device__ __forceinline__ void gld_lds16(void* lds, const void* g) {
    __builtin_amdgcn_global_load_lds(
        (const __attribute__((address_space(1))) unsigned int*)g,
        (__attribute__((address_space(3))) unsigned int*)lds, 16, 0, 0);
}

// ---------------- zero (float4 granularity) ----------------
__global__ void k_zero(float* __restrict__ p, int n4) {
    int i = blockIdx.x * 256 + threadIdx.x;
    if (i < n4) ((float4*)p)[i] = make_float4(0.f, 0.f, 0.f, 0.f);
}

// ---------------- CSR build: histogram, 3-phase scan, scatter ----------------
__global__ void k_hist(const int* __restrict__ dst, int* __restrict__ deg) {
    int e = blockIdx.x * 256 + threadIdx.x;
    if (e < N_EDGES) atomicAdd(&deg[dst[e]], 1);
}

__global__ void __launch_bounds__(256) k_scan_a(
    const int* __restrict__ deg, int* __restrict__ row_start, int* __restrict__ bsum) {
    __shared__ int s[256];
    int t = threadIdx.x;
    int idx = blockIdx.x * 256 + t;
    int v = (idx < N_NODES) ? deg[idx] : 0;
    s[t] = v;
    __syncthreads();
    for (int off = 1; off < 256; off <<= 1) {
        int u = (t >= off) ? s[t - off] : 0;
        __syncthreads();
        s[t] += u;
        __syncthreads();
    }
    if (idx < N_NODES) row_start[idx] = s[t] - v;   // local exclusive
    if (t == 255) bsum[blockIdx.x] = s[255];
}

__global__ void __launch_bounds__(256) k_scan_b(int* __restrict__ bsum,
                                                int* __restrict__ boff) {
    __shared__ int s[256];
    int t = threadIdx.x;
    int v = (t < SCAN_BLKS) ? bsum[t] : 0;
    s[t] = v;
    __syncthreads();
    for (int off = 1; off < 256; off <<= 1) {
        int u = (t >= off) ? s[t - off] : 0;
        __syncthreads();
        s[t] += u;
        __syncthreads();
    }
    if (t < SCAN_BLKS) boff[t] = s[t] - v;          // exclusive
}

__global__ void __launch_bounds__(256) k_scan_c(
    int* __restrict__ row_start, const int* __restrict__ boff,
    int* __restrict__ cursor) {
    int idx = blockIdx.x * 256 + threadIdx.x;
    if (idx < N_NODES) {
        int r = row_start[idx] + boff[blockIdx.x];
        row_start[idx] = r;
        cursor[idx] = r;
    }
    if (idx == 0) row_start[N_NODES] = N_EDGES;
}

// packed payload: (src << 5) | ety   (src < 2^17, ety < 32)
__global__ void k_scatter(const int* __restrict__ src, const int* __restrict__ dst,
                          const int* __restrict__ ety, int* __restrict__ cursor,
                          int* __restrict__ edge_p) {
    int e = blockIdx.x * 256 + threadIdx.x;
    if (e >= N_EDGES) return;
    int d = dst[e];
    int pos = atomicAdd(&cursor[d], 1);
    edge_p[pos] = (src[e] << 5) | ety[e];
}

// ---------------- input projection (16 nodes/block): h = relu([feat, er] @ W_in + b_in) ----------------
__global__ void __launch_bounds__(128) k_input(
    const float* __restrict__ feat, const int* __restrict__ qrel,
    const float* __restrict__ rel_emb, const float* __restrict__ Wi,
    const float* __restrict__ bi, float* __restrict__ h,
    unsigned short* __restrict__ h16, float* __restrict__ er) {
    int n0 = blockIdx.x * 16;
    int j = threadIdx.x;
    int u = j >> 3, q = j & 7;
    __shared__ float xT[96][16];
    {
        const float4* f4 = (const float4*)(feat + (size_t)(n0 + u) * IN_FEAT);
        float4 a = f4[q], b = f4[q + 8];
        xT[4 * q + 0][u] = a.x; xT[4 * q + 1][u] = a.y;
        xT[4 * q + 2][u] = a.z; xT[4 * q + 3][u] = a.w;
        xT[32 + 4 * q + 0][u] = b.x; xT[32 + 4 * q + 1][u] = b.y;
        xT[32 + 4 * q + 2][u] = b.z; xT[32 + 4 * q + 3][u] = b.w;
        int qr = qrel[n0 + u];
        float4 e4 = ((const float4*)(rel_emb + (size_t)qr * REL_DIM))[q];
        xT[64 + 4 * q + 0][u] = e4.x; xT[64 + 4 * q + 1][u] = e4.y;
        xT[64 + 4 * q + 2][u] = e4.z; xT[64 + 4 * q + 3][u] = e4.w;
        ((float4*)(er + (size_t)(n0 + u) * REL_DIM))[q] = e4;
    }
    __syncthreads();
    float bj = bi[j];
    float acc[16];
#pragma unroll
    for (int k = 0; k < 16; k++) acc[k] = bj;
    for (int d = 0; d < 96; d++) {
        float w = Wi[d * HID + j];
        float4 x0 = *(const float4*)&xT[d][0];
        float4 x1 = *(const float4*)&xT[d][4];
        float4 x2 = *(const float4*)&xT[d][8];
        float4 x3 = *(const float4*)&xT[d][12];
        acc[0]  = fmaf(x0.x, w, acc[0]);  acc[1]  = fmaf(x0.y, w, acc[1]);
        acc[2]  = fmaf(x0.z, w, acc[2]);  acc[3]  = fmaf(x0.w, w, acc[3]);
        acc[4]  = fmaf(x1.x, w, acc[4]);  acc[5]  = fmaf(x1.y, w, acc[5]);
        acc[6]  = fmaf(x1.z, w, acc[6]);  acc[7]  = fmaf(x1.w, w, acc[7]);
        acc[8]  = fmaf(x2.x, w, acc[8]);  acc[9]  = fmaf(x2.y, w, acc[9]);
        acc[10] = fmaf(x2.z, w, acc[10]); acc[11] = fmaf(x2.w, w, acc[11]);
        acc[12] = fmaf(x3.x, w, acc[12]); acc[13] = fmaf(x3.y, w, acc[13]);
        acc[14] = fmaf(x3.z, w, acc[14]); acc[15] = fmaf(x3.w, w, acc[15]);
    }
#pragma unroll
    for (int k = 0; k < 16; k++) {
        float v = fmaxf(acc[k], 0.f);
        h[(size_t)(n0 + k) * HID + j] = v;
        __half hv = __float2half(v);
        h16[(size_t)(n0 + k) * HID + j] = __builtin_bit_cast(unsigned short, hv);
    }
}

// ---------------- per-dst basis-weighted gather (fp16 h), 8-deep MLP, fp16 G output ----------------
// Gf[n-c0][b*128+d] = fp16( sum_e c[ety,b]*h16[src,d] )
__global__ void __launch_bounds__(256) k_mix2(
    const unsigned short* __restrict__ h16, const float* __restrict__ comp_l,
    const int* __restrict__ row_start, const int* __restrict__ edge_p,
    unsigned short* __restrict__ Gf, int c0, int nc) {
    __shared__ float cs[NUM_RELS * NUM_BASES];
    if (threadIdx.x < NUM_RELS * NUM_BASES) cs[threadIdx.x] = comp_l[threadIdx.x];
    __syncthreads();
    int wave = threadIdx.x >> 6, lane = threadIdx.x & 63;
    int n = c0 + blockIdx.x * 4 + wave;
    if (n >= c0 + nc) return;
    int e0 = row_start[n], e1 = row_start[n + 1];
    float2 acc[NUM_BASES];
#pragma unroll
    for (int b = 0; b < NUM_BASES; b++) acc[b] = make_float2(0.f, 0.f);
    int e = e0;
    // 8-deep unroll: issue 8 independent row-gathers before consuming any
    for (; e + 8 <= e1; e += 8) {
        int p0 = edge_p[e],     p1 = edge_p[e + 1], p2 = edge_p[e + 2], p3 = edge_p[e + 3];
        int p4 = edge_p[e + 4], p5 = edge_p[e + 5], p6 = edge_p[e + 6], p7 = edge_p[e + 7];
        unsigned u0 = ((const unsigned*)(h16 + (size_t)(p0 >> 5) * HID))[lane];
        unsigned u1 = ((const unsigned*)(h16 + (size_t)(p1 >> 5) * HID))[lane];
        unsigned u2 = ((const unsigned*)(h16 + (size_t)(p2 >> 5) * HID))[lane];
        unsigned u3 = ((const unsigned*)(h16 + (size_t)(p3 >> 5) * HID))[lane];
        unsigned u4 = ((const unsigned*)(h16 + (size_t)(p4 >> 5) * HID))[lane];
        unsigned u5 = ((const unsigned*)(h16 + (size_t)(p5 >> 5) * HID))[lane];
        unsigned u6 = ((const unsigned*)(h16 + (size_t)(p6 >> 5) * HID))[lane];
        unsigned u7 = ((const unsigned*)(h16 + (size_t)(p7 >> 5) * HID))[lane];
        const float* c0p = &cs[(p0 & 31) * NUM_BASES];
        const float* c1p = &cs[(p1 & 31) * NUM_BASES];
        const float* c2p = &cs[(p2 & 31) * NUM_BASES];
        const float* c3p = &cs[(p3 & 31) * NUM_BASES];
        const float* c4p = &cs[(p4 & 31) * NUM_BASES];
        const float* c5p = &cs[(p5 & 31) * NUM_BASES];
        const float* c6p = &cs[(p6 & 31) * NUM_BASES];
        const float* c7p = &cs[(p7 & 31) * NUM_BASES];
        float2 v0 = __half22float2(__builtin_bit_cast(__half2, u0));
        float2 v1 = __half22float2(__builtin_bit_cast(__half2, u1));
        float2 v2 = __half22float2(__builtin_bit_cast(__half2, u2));
        float2 v3 = __half22float2(__builtin_bit_cast(__half2, u3));
        float2 v4 = __half22float2(__builtin_bit_cast(__half2, u4));
        float2 v5 = __half22float2(__builtin_bit_cast(__half2, u5));
        float2 v6 = __half22float2(__builtin_bit_cast(__half2, u6));
        float2 v7 = __half22float2(__builtin_bit_cast(__half2, u7));
#pragma unroll
        for (int b = 0; b < NUM_BASES; b++) {
            acc[b].x = fmaf(c0p[b], v0.x, acc[b].x);
            acc[b].y = fmaf(c0p[b], v0.y, acc[b].y);
            acc[b].x = fmaf(c1p[b], v1.x, acc[b].x);
            acc[b].y = fmaf(c1p[b], v1.y, acc[b].y);
            acc[b].x = fmaf(c2p[b], v2.x, acc[b].x);
            acc[b].y = fmaf(c2p[b], v2.y, acc[b].y);
            acc[b].x = fmaf(c3p[b], v3.x, acc[b].x);
            acc[b].y = fmaf(c3p[b], v3.y, acc[b].y);
            acc[b].x = fmaf(c4p[b], v4.x, acc[b].x);
            acc[b].y = fmaf(c4p[b], v4.y, acc[b].y);
            acc[b].x = fmaf(c5p[b], v5.x, acc[b].x);
            acc[b].y = fmaf(c5p[b], v5.y, acc[b].y);
            acc[b].x = fmaf(c6p[b], v6.x, acc[b].x);
            acc[b].y = fmaf(c6p[b], v6.y, acc[b].y);
            acc[b].x = fmaf(c7p[b], v7.x, acc[b].x);
            acc[b].y = fmaf(c7p[b], v7.y, acc[b].y);
        }
    }
    for (; e < e1; e++) {
        int se = edge_p[e];
        const float* c = &cs[(se & 31) * NUM_BASES];
        unsigned u = ((const unsigned*)(h16 + (size_t)(se >> 5) * HID))[lane];
        float2 v = __half22float2(__builtin_bit_cast(__half2, u));
#pragma unroll
        for (int b = 0; b < NUM_BASES; b++) {
            acc[b].x = fmaf(c[b], v.x, acc[b].x);
            acc[b].y = fmaf(c[b], v.y, acc[b].y);
        }
    }
    size_t base = (size_t)(n - c0) * 1024 + 2 * lane;
#pragma unroll
    for (int b = 0; b < NUM_BASES; b++) {
        __half2 g2 = __floats2half2_rn(acc[b].x, acc[b].y);
        *(unsigned*)&Gf[base + b * 128] = __builtin_bit_cast(unsigned, g2);
    }
}

// ---------------- B fragment table: f16 (hi only) of [Vl ; Wl], MFMA fragment order ----------------
// entry (l, s, t, lane): 8 ushort; element j:
// B[k = s*32 + (lane>>4)*8 + j][col = t*16 + (lane&15)] of layer l.
__global__ void k_bfrag(const float* __restrict__ V, const float* __restrict__ W_loop,
                        unsigned short* __restrict__ Bf) {
    int idx = blockIdx.x * 256 + threadIdx.x;
    if (idx >= NUM_LAYERS * 36 * 8 * 64) return;
    int lane = idx & 63;
    int t = (idx >> 6) & 7;
    int s = (idx >> 9) % 36;
    int l = (idx >> 9) / 36;
    int col = t * 16 + (lane & 15);
    int kbase = s * 32 + (lane >> 4) * 8;
    unsigned short* o = Bf + (size_t)idx * 8;
#pragma unroll
    for (int j = 0; j < 8; j++) {
        int k = kbase + j;
        float f = (k < 1024) ? V[((size_t)l * 1024 + k) * HID + col]
                             : W_loop[((size_t)l * HID + (k - 1024)) * HID + col];
        __half hh = __float2half(f);
        o[j] = __builtin_bit_cast(unsigned short, hh);
    }
}

// ---------------- f16 MFMA GEMM (BM=64, BK=128, single-B): 8 barriers, 32 MFMA/wave/barrier ----------------
// out = relu([G | h] @ f16([Vl ; Wl]) + bl); also fp16 copy.  M=nc, K=1152, N=128.
// Block = 64 rows x 128 cols, 4 waves col-split (wave w -> t=2w,2w+1), 4 rowgroups.
// LDS: 2 bufs x 16 frags (4 k-subtiles x 4 rowgroups) x 1KB = 32KB, lane-linear.
__global__ void __launch_bounds__(256) k_gemm9(
    const unsigned short* __restrict__ Gf, const unsigned short* __restrict__ h16,
    const unsigned short* __restrict__ Bf, const float* __restrict__ bl,
    float* __restrict__ out, unsigned short* __restrict__ out16, int c0, int nc) {
    __shared__ unsigned short smem[2][16][512];  // [buf][frag][1KB] = 32KB
    int lane = threadIdx.x & 63;
    int w = threadIdx.x >> 6;
    int rit = lane & 15, kg = lane >> 4;
    int r0 = blockIdx.x * 64;
    int sr0 = r0 + 0 * 16 + rit; if (sr0 >= nc) sr0 = nc - 1;
    int sr1 = r0 + 1 * 16 + rit; if (sr1 >= nc) sr1 = nc - 1;
    int sr2 = r0 + 2 * 16 + rit; if (sr2 >= nc) sr2 = nc - 1;
    int sr3 = r0 + 3 * 16 + rit; if (sr3 >= nc) sr3 = nc - 1;
    int koff = w * 32 + kg * 8;
    const unsigned short* gs0 = Gf + (size_t)sr0 * 1024 + koff;
    const unsigned short* gs1 = Gf + (size_t)sr1 * 1024 + koff;
    const unsigned short* gs2 = Gf + (size_t)sr2 * 1024 + koff;
    const unsigned short* gs3 = Gf + (size_t)sr3 * 1024 + koff;
    // B entries: 1 f16x8 per (s,t,lane); per s: 8 t x 64 lanes = 512 entries
    const f16x8* bb = (const f16x8*)Bf + (size_t)(2 * w) * 64 + lane;
    f32x4 acc[4][2] = {};

#define STAGE(BUF, STEP) {                                        \
        gld_lds16(&smem[BUF][w * 4 + 0][0], gs0 + (STEP) * 128);  \
        gld_lds16(&smem[BUF][w * 4 + 1][0], gs1 + (STEP) * 128);  \
        gld_lds16(&smem[BUF][w * 4 + 2][0], gs2 + (STEP) * 128);  \
        gld_lds16(&smem[BUF][w * 4 + 3][0], gs3 + (STEP) * 128); }
#define CSTEP(BUF, STEP) _Pragma("unroll")                                   \
    for (int s = 0; s < 4; s++) {                                            \
        const f16x8* bp = bb + (size_t)((STEP) * 4 + s) * 512;               \
        f16x8 bh0 = bp[0], bh1 = bp[64];                                     \
        _Pragma("unroll")                                                    \
        for (int i = 0; i < 4; i++) {                                        \
            f16x8 a = *(const f16x8*)&smem[BUF][s * 4 + i][lane * 8];        \
            acc[i][0] = __builtin_amdgcn_mfma_f32_16x16x32_f16(a, bh0, acc[i][0], 0, 0, 0); \
            acc[i][1] = __builtin_amdgcn_mfma_f32_16x16x32_f16(a, bh1, acc[i][1], 0, 0, 0); \
        }                                                                    \
    }

    STAGE(0, 0);
    for (int t = 0; t < 8; t++) {
        __syncthreads();
        if (t < 7) STAGE((t + 1) & 1, t + 1);
        CSTEP(t & 1, t);
    }
    // K tail 1024..1151 (self-loop) straight from fp16 h16
    {
        const unsigned short* hp0 = h16 + (size_t)(c0 + sr0) * HID + kg * 8;
        const unsigned short* hp1 = h16 + (size_t)(c0 + sr1) * HID + kg * 8;
        const unsigned short* hp2 = h16 + (size_t)(c0 + sr2) * HID + kg * 8;
        const unsigned short* hp3 = h16 + (size_t)(c0 + sr3) * HID + kg * 8;
#pragma unroll
        for (int s = 32; s < 36; s++) {
            int o = (s - 32) * 32;
            f16x8 a0 = *(const f16x8*)(hp0 + o);
            f16x8 a1 = *(const f16x8*)(hp1 + o);
            f16x8 a2 = *(const f16x8*)(hp2 + o);
            f16x8 a3 = *(const f16x8*)(hp3 + o);
            const f16x8* bp = bb + (size_t)s * 512;
            f16x8 bh0 = bp[0], bh1 = bp[64];
            acc[0][0] = __builtin_amdgcn_mfma_f32_16x16x32_f16(a0, bh0, acc[0][0], 0, 0, 0);
            acc[0][1] = __builtin_amdgcn_mfma_f32_16x16x32_f16(a0, bh1, acc[0][1], 0, 0, 0);
            acc[1][0] = __builtin_amdgcn_mfma_f32_16x16x32_f16(a1, bh0, acc[1][0], 0, 0, 0);
            acc[1][1] = __builtin_amdgcn_mfma_f32_16x16x32_f16(a1, bh1, acc[1][1], 0, 0, 0);
            acc[2][0] = __builtin_amdgcn_mfma_f32_16x16x32_f16(a2, bh0, acc[2][0], 0, 0, 0);
            acc[2][1] = __builtin_amdgcn_mfma_f32_16x16x32_f16(a2, bh1, acc[2][1], 0, 0, 0);
            acc[3][0] = __builtin_amdgcn_mfma_f32_16x16x32_f16(a3, bh0, acc[3][0], 0, 0, 0);
            acc[3][1] = __builtin_amdgcn_mfma_f32_16x16x32_f16(a3, bh1, acc[3][1], 0, 0, 0);
        }
    }
#undef STAGE
#undef CSTEP
    int col0 = 2 * w * 16 + rit;
    float b0 = bl[col0], b1 = bl[col0 + 16];
#pragma unroll
    for (int i = 0; i < 4; i++) {
        int rq = r0 + i * 16 + kg * 4;
#pragma unroll
        for (int q = 0; q < 4; q++) {
            int row = rq + q;
            if (row < nc) {
                float v0 = fmaxf(acc[i][0][q] + b0, 0.f);
                float v1 = fmaxf(acc[i][1][q] + b1, 0.f);
                size_t o = (size_t)(c0 + row) * HID;
                out[o + col0] = v0; out[o + col0 + 16] = v1;
                out16[o + col0] = __builtin_bit_cast(unsigned short, __float2half(v0));
                out16[o + col0 + 16] = __builtin_bit_cast(unsigned short, __float2half(v1));
            }
        }
    }
}

// ---------------- attention scalar score per node (16 nodes/block) ----------------
__global__ void __launch_bounds__(128) k_score(
    const float* __restrict__ h, const float* __restrict__ er,
    const float* __restrict__ Wa, const float* __restrict__ ba,
    const float* __restrict__ wsc, const float* __restrict__ bsc,
    float* __restrict__ a) {
    int n0 = blockIdx.x * 16;
    int j = threadIdx.x;
    int u = j >> 3, q = j & 7;
    __shared__ float xT[160][16];
    {
        const float4* h4 = (const float4*)(h + (size_t)(n0 + u) * HID);
#pragma unroll
        for (int k = 0; k < 4; k++) {
            float4 v = h4[q + 8 * k];
            xT[32 * k + 4 * q + 0][u] = v.x; xT[32 * k + 4 * q + 1][u] = v.y;
            xT[32 * k + 4 * q + 2][u] = v.z; xT[32 * k + 4 * q + 3][u] = v.w;
        }
        float4 e4 = ((const float4*)(er + (size_t)(n0 + u) * REL_DIM))[q];
        xT[128 + 4 * q + 0][u] = e4.x; xT[128 + 4 * q + 1][u] = e4.y;
        xT[128 + 4 * q + 2][u] = e4.z; xT[128 + 4 * q + 3][u] = e4.w;
    }
    __syncthreads();
    float bj = ba[j];
    float acc[16];
#pragma unroll
    for (int k = 0; k < 16; k++) acc[k] = bj;
    for (int d = 0; d < 160; d++) {
        float w = Wa[d * HID + j];
        float4 x0 = *(const float4*)&xT[d][0];
        float4 x1 = *(const float4*)&xT[d][4];
        float4 x2 = *(const float4*)&xT[d][8];
        float4 x3 = *(const float4*)&xT[d][12];
        acc[0]  = fmaf(x0.x, w, acc[0]);  acc[1]  = fmaf(x0.y, w, acc[1]);
        acc[2]  = fmaf(x0.z, w, acc[2]);  acc[3]  = fmaf(x0.w, w, acc[3]);
        acc[4]  = fmaf(x1.x, w, acc[4]);  acc[5]  = fmaf(x1.y, w, acc[5]);
        acc[6]  = fmaf(x1.z, w, acc[6]);  acc[7]  = fmaf(x1.w, w, acc[7]);
        acc[8]  = fmaf(x2.x, w, acc[8]);  acc[9]  = fmaf(x2.y, w, acc[9]);
        acc[10] = fmaf(x2.z, w, acc[10]); acc[11] = fmaf(x2.w, w, acc[11]);
        acc[12] = fmaf(x3.x, w, acc[12]); acc[13] = fmaf(x3.y, w, acc[13]);
        acc[14] = fmaf(x3.z, w, acc[14]); acc[15] = fmaf(x3.w, w, acc[15]);
    }
    __shared__ float red[16][128];
    float wj = wsc[j];
#pragma unroll
    for (int k = 0; k < 16; k++) red[k][j] = tanhf(acc[k]) * wj;
    __syncthreads();
    for (int s = 64; s > 0; s >>= 1) {
        if (j < s) {
#pragma unroll
            for (int k = 0; k < 16; k++) red[k][j] += red[k][j + s];
        }
        __syncthreads();
    }
    if (j < 16) a[n0 + j] = red[j][0] + bsc[0];
}

// ---------------- graph boundaries (graph_id is sorted) ----------------
__global__ void k_starts(const int* __restrict__ gid, int* __restrict__ starts) {
    int g = threadIdx.x;  // 0..255
    int lo = 0, hi = N_NODES;
    while (lo < hi) {
        int mid = (lo + hi) >> 1;
        if (gid[mid] < g) lo = mid + 1; else hi = mid;
    }
    starts[g] = lo;
    if (g == 0) starts[NUM_GRAPHS] = N_NODES;
}

// ---------------- segment softmax pooling + final dot ----------------
__global__ void __launch_bounds__(128) k_pool(
    const float* __restrict__ h, const float* __restrict__ a,
    const int* __restrict__ starts, const float* __restrict__ wout,
    const float* __restrict__ bout, float* __restrict__ out) {
    int g = blockIdx.x, j = threadIdx.x;
    int s0 = starts[g], s1 = starts[g + 1];
    __shared__ float red[128];
    __shared__ float exb[128];
    if (s1 <= s0) { if (j == 0) out[g] = bout[0]; return; }
    float m = -3.4e38f;
    for (int i = s0 + j; i < s1; i += 128) m = fmaxf(m, a[i]);
    red[j] = m; __syncthreads();
    for (int s = 64; s > 0; s >>= 1) {
        if (j < s) red[j] = fmaxf(red[j], red[j + s]);
        __syncthreads();
    }
    m = red[0]; __syncthreads();
    float zj = 0.f, ss = 0.f;
    for (int base = s0; base < s1; base += 128) {
        int cnt = min(128, s1 - base);
        float ev = 0.f;
        if (j < cnt) ev = expf(a[base + j] - m);
        exb[j] = ev;
        ss += ev;
        __syncthreads();
        for (int k = 0; k < cnt; k++)
            zj = fmaf(exb[k], h[(size_t)(base + k) * HID + j], zj);
        __syncthreads();
    }
    red[j] = ss; __syncthreads();
    for (int s = 64; s > 0; s >>= 1) {
        if (j < s) red[j] += red[j + s];
        __syncthreads();
    }
    ss = red[0]; __syncthreads();
    red[j] = (zj / ss) * wout[j]; __syncthreads();
    for (int s = 64; s > 0; s >>= 1) {
        if (j < s) red[j] += red[j + s];
        __syncthreads();
    }
    if (j == 0) out[g] = red[0] + bout[0];
}

extern "C" void kernel_launch(void* const* d_in, const int* in_sizes, int n_in,
                              void* d_out, int out_size, void* d_ws, size_t ws_size,
                              hipStream_t stream) {
    const float* feat    = (const float*)d_in[0];
    const int*   qrel    = (const int*)d_in[1];
    const int*   src     = (const int*)d_in[2];
    const int*   dst     = (const int*)d_in[3];
    const int*   ety     = (const int*)d_in[4];
    const int*   gid     = (const int*)d_in[5];
    const float* rel_emb = (const float*)d_in[6];
    const float* W_in    = (const float*)d_in[7];
    const float* b_in    = (const float*)d_in[8];
    const float* V       = (const float*)d_in[9];
    const float* comp    = (const float*)d_in[10];
    const float* W_loop  = (const float*)d_in[11];
    const float* b_loop  = (const float*)d_in[12];
    const float* W_attn  = (const float*)d_in[13];
    const float* b_attn  = (const float*)d_in[14];
    const float* w_sc    = (const float*)d_in[15];
    const float* b_sc    = (const float*)d_in[16];
    const float* w_out   = (const float*)d_in[17];
    const float* b_out   = (const float*)d_in[18];
    float* out = (float*)d_out;

    float* ws = (float*)d_ws;
    float* h0 = ws;                                       // 6.4M floats
    float* h1 = h0 + (size_t)N_NODES * HID;               // 6.4M
    unsigned short* h16a = (unsigned short*)(h1 + (size_t)N_NODES * HID);  // 6.4M ushort
    unsigned short* h16b = h16a + (size_t)N_NODES * HID;                   // 6.4M ushort
    float* er = (float*)(h16b + (size_t)N_NODES * HID);   // 1.6M
    float* af = er + (size_t)N_NODES * REL_DIM;           // 50000
    int* starts    = (int*)(af + N_NODES);                // 260
    int* deg       = starts + 260;                        // 50000
    int* row_start = deg + 50000;                         // 50004
    int* cursor    = row_start + 50004;                   // 50000
    int* bsum      = cursor + 50000;                      // 256
    int* boff      = bsum + 256;                          // 256
    int* edge_p    = boff + 256;                          // 800000 packed ints
    unsigned short* Bf = (unsigned short*)(edge_p + 800000);  // 2*36*8*64*8 ushort (hi only)
    const size_t BF_USHORT = (size_t)NUM_LAYERS * 36 * 8 * 64 * 8;
    unsigned short* Gf = Bf + BF_USHORT;

    size_t used_floats = (size_t)((float*)Gf - ws);
    size_t total_floats = ws_size / sizeof(float);
    size_t avail = (total_floats > used_floats) ? (total_floats - used_floats) : 0;
    long long NC = (long long)(avail / 512);   // 1024 fp16 per row = 512 floats
    NC = (NC / 64) * 64;
    if (NC > 50048) NC = 50048;
    if (NC < 64) NC = 64;

    // --- preprocessing ---
    k_zero<<<(12500 + 255) / 256, 256, 0, stream>>>((float*)deg, 12500);
    k_hist<<<(N_EDGES + 255) / 256, 256, 0, stream>>>(dst, deg);
    k_scan_a<<<SCAN_BLKS, 256, 0, stream>>>(deg, row_start, bsum);
    k_scan_b<<<1, 256, 0, stream>>>(bsum, boff);
    k_scan_c<<<SCAN_BLKS, 256, 0, stream>>>(row_start, boff, cursor);
    k_scatter<<<(N_EDGES + 255) / 256, 256, 0, stream>>>(src, dst, ety, cursor, edge_p);
    k_bfrag<<<(NUM_LAYERS * 36 * 8 * 64 + 255) / 256, 256, 0, stream>>>(V, W_loop, Bf);
    k_input<<<N_NODES / 16, 128, 0, stream>>>(feat, qrel, rel_emb, W_in, b_in, h0, h16a, er);

    float* hcur = h0;
    float* hnext = h1;
    unsigned short* h16cur = h16a;
    unsigned short* h16next = h16b;
    for (int l = 0; l < NUM_LAYERS; l++) {
        const float* comp_l = comp + (size_t)l * NUM_RELS * NUM_BASES;
        const unsigned short* Bfl = Bf + (size_t)l * 36 * 8 * 64 * 8;
        const float* bl = b_loop + (size_t)l * HID;
        for (int c0 = 0; c0 < N_NODES; c0 += (int)NC) {
            int nc = (int)((N_NODES - c0 < NC) ? (N_NODES - c0) : NC);
            k_mix2<<<(nc + 3) / 4, 256, 0, stream>>>(h16cur, comp_l, row_start, edge_p,
                                                     Gf, c0, nc);
            k_gemm9<<<(nc + 63) / 64, 256, 0, stream>>>(Gf, h16cur, Bfl, bl,
                                                        hnext, h16next, c0, nc);
        }
        float* tmp = hcur; hcur = hnext; hnext = tmp;
        unsigned short* tmp16 = h16cur; h16cur = h16next; h16next = tmp16;
    }

    k_score<<<N_NODES / 16, 128, 0, stream>>>(hcur, er, W_attn, b_attn, w_sc, b_sc, af);
    k_starts<<<1, 256, 0, stream>>>(gid, starts);
    k_pool<<<NUM_GRAPHS, 128, 0, stream>>>(hcur, af, starts, w_out, b_out, out);
}

// Round 15
// 328.408 us; speedup vs baseline: 1.9235x; 1.2174x over previous
//
#include <hip/hip_runtime.h>
#include <hip/hip_fp16.h>

#define N_NODES   50000
#define N_EDGES   800000
#define NUM_GRAPHS 256
#define IN_FEAT   64
#define REL_DIM   32
#define HID       128
#define NUM_RELS  32
#define NUM_BASES 8
#define NUM_LAYERS 2

#define NBUCK 196            // dst >> 8
#define PBLK  512            // scatter blocks
#define CHUNK 1563           // ceil(800000/512)
#define OFFN  (NBUCK * PBLK) // 100352
#define SC2_BLKS (OFFN / 256)  // 392

typedef __attribute__((ext_vector_type(8))) _Float16 f16x8;
typedef __attribute__((ext_vector_type(4))) float f32x4;

// async 16B global -> LDS (wave-uniform LDS base + lane*16; per-lane global src)
__device__ __forceinline__ void gld_lds16(void* lds, const void* g) {
    __builtin_amdgcn_global_load_lds(
        (const __attribute__((address_space(1))) unsigned int*)g,
        (__attribute__((address_space(3))) unsigned int*)lds, 16, 0, 0);
}

// ---------------- edge sort phase A: per-(block,bucket) histogram ----------------
__global__ void __launch_bounds__(256) k_bhist(const int* __restrict__ dst,
                                               int* __restrict__ off) {
    __shared__ int hist[NBUCK];
    int t = threadIdx.x;
    if (t < NBUCK) hist[t] = 0;
    __syncthreads();
    int base = blockIdx.x * CHUNK;
    for (int i = t; i < CHUNK; i += 256) {
        int e = base + i;
        if (e < N_EDGES) atomicAdd(&hist[dst[e] >> 8], 1);
    }
    __syncthreads();
    if (t < NBUCK) off[t * PBLK + blockIdx.x] = hist[t];
}

// ---------------- phase B: multi-block exclusive scan of off[OFFN] ----------------
__global__ void __launch_bounds__(256) k_scan2_a(int* __restrict__ off,
                                                 int* __restrict__ bsum) {
    __shared__ int s[256];
    int t = threadIdx.x;
    int idx = blockIdx.x * 256 + t;
    int v = off[idx];
    s[t] = v;
    __syncthreads();
    for (int o = 1; o < 256; o <<= 1) {
        int u = (t >= o) ? s[t - o] : 0;
        __syncthreads();
        s[t] += u;
        __syncthreads();
    }
    off[idx] = s[t] - v;                 // local exclusive
    if (t == 255) bsum[blockIdx.x] = s[255];
}

__global__ void __launch_bounds__(512) k_scan2_b(int* __restrict__ bsum,
                                                 int* __restrict__ boff) {
    __shared__ int s[512];
    int t = threadIdx.x;
    int v = (t < SC2_BLKS) ? bsum[t] : 0;
    s[t] = v;
    __syncthreads();
    for (int o = 1; o < 512; o <<= 1) {
        int u = (t >= o) ? s[t - o] : 0;
        __syncthreads();
        s[t] += u;
        __syncthreads();
    }
    if (t < SC2_BLKS) boff[t] = s[t] - v;   // exclusive
}

__global__ void __launch_bounds__(256) k_scan2_c(int* __restrict__ off,
                                                 const int* __restrict__ boff) {
    int idx = blockIdx.x * 256 + threadIdx.x;
    off[idx] += boff[blockIdx.x];
}

// ---------------- phase C: bucket-scatter (packed (dl<<21)|(src<<5)|ety) ----------------
__global__ void __launch_bounds__(256) k_bscatter(
    const int* __restrict__ src, const int* __restrict__ dst,
    const int* __restrict__ ety, const int* __restrict__ off,
    int* __restrict__ tmp) {
    __shared__ int cur[NBUCK];
    int t = threadIdx.x;
    if (t < NBUCK) cur[t] = off[t * PBLK + blockIdx.x];
    __syncthreads();
    int base = blockIdx.x * CHUNK;
    for (int i = t; i < CHUNK; i += 256) {
        int e = base + i;
        if (e < N_EDGES) {
            int d = dst[e];
            int pos = atomicAdd(&cur[d >> 8], 1);
            tmp[pos] = ((d & 255) << 21) | (src[e] << 5) | ety[e];
        }
    }
}

// ---------------- phase D: per-bucket counting sort by dst_local; emits row_start ----------------
__global__ void __launch_bounds__(256) k_bsort(
    const int* __restrict__ off, const int* __restrict__ tmp,
    int* __restrict__ edge_p, int* __restrict__ row_start) {
    int b = blockIdx.x, t = threadIdx.x;
    int eb = off[b * PBLK];
    int ee = (b == NBUCK - 1) ? N_EDGES : off[(b + 1) * PBLK];
    __shared__ int cnt[256];
    __shared__ int cur[256];
    cnt[t] = 0;
    __syncthreads();
    for (int i = eb + t; i < ee; i += 256)
        atomicAdd(&cnt[(tmp[i] >> 21) & 255], 1);
    __syncthreads();
    // exclusive scan of cnt
    int v = cnt[t];
    __shared__ int s[256];
    s[t] = v;
    __syncthreads();
    for (int o = 1; o < 256; o <<= 1) {
        int u = (t >= o) ? s[t - o] : 0;
        __syncthreads();
        s[t] += u;
        __syncthreads();
    }
    int excl = s[t] - v;
    cur[t] = eb + excl;
    int node = b * 256 + t;
    if (node < N_NODES) row_start[node] = eb + excl;
    if (b == NBUCK - 1 && t == 0) row_start[N_NODES] = N_EDGES;
    __syncthreads();
    for (int i = eb + t; i < ee; i += 256) {
        int x = tmp[i];
        int pos = atomicAdd(&cur[(x >> 21) & 255], 1);
        edge_p[pos] = x & 0x1FFFFF;      // (src<<5)|ety
    }
}

// ---------------- input projection (16 nodes/block): h = relu([feat, er] @ W_in + b_in) ----------------
__global__ void __launch_bounds__(128) k_input(
    const float* __restrict__ feat, const int* __restrict__ qrel,
    const float* __restrict__ rel_emb, const float* __restrict__ Wi,
    const float* __restrict__ bi, float* __restrict__ h,
    unsigned short* __restrict__ h16, float* __restrict__ er) {
    int n0 = blockIdx.x * 16;
    int j = threadIdx.x;
    int u = j >> 3, q = j & 7;
    __shared__ float xT[96][16];
    {
        const float4* f4 = (const float4*)(feat + (size_t)(n0 + u) * IN_FEAT);
        float4 a = f4[q], b = f4[q + 8];
        xT[4 * q + 0][u] = a.x; xT[4 * q + 1][u] = a.y;
        xT[4 * q + 2][u] = a.z; xT[4 * q + 3][u] = a.w;
        xT[32 + 4 * q + 0][u] = b.x; xT[32 + 4 * q + 1][u] = b.y;
        xT[32 + 4 * q + 2][u] = b.z; xT[32 + 4 * q + 3][u] = b.w;
        int qr = qrel[n0 + u];
        float4 e4 = ((const float4*)(rel_emb + (size_t)qr * REL_DIM))[q];
        xT[64 + 4 * q + 0][u] = e4.x; xT[64 + 4 * q + 1][u] = e4.y;
        xT[64 + 4 * q + 2][u] = e4.z; xT[64 + 4 * q + 3][u] = e4.w;
        ((float4*)(er + (size_t)(n0 + u) * REL_DIM))[q] = e4;
    }
    __syncthreads();
    float bj = bi[j];
    float acc[16];
#pragma unroll
    for (int k = 0; k < 16; k++) acc[k] = bj;
    for (int d = 0; d < 96; d++) {
        float w = Wi[d * HID + j];
        float4 x0 = *(const float4*)&xT[d][0];
        float4 x1 = *(const float4*)&xT[d][4];
        float4 x2 = *(const float4*)&xT[d][8];
        float4 x3 = *(const float4*)&xT[d][12];
        acc[0]  = fmaf(x0.x, w, acc[0]);  acc[1]  = fmaf(x0.y, w, acc[1]);
        acc[2]  = fmaf(x0.z, w, acc[2]);  acc[3]  = fmaf(x0.w, w, acc[3]);
        acc[4]  = fmaf(x1.x, w, acc[4]);  acc[5]  = fmaf(x1.y, w, acc[5]);
        acc[6]  = fmaf(x1.z, w, acc[6]);  acc[7]  = fmaf(x1.w, w, acc[7]);
        acc[8]  = fmaf(x2.x, w, acc[8]);  acc[9]  = fmaf(x2.y, w, acc[9]);
        acc[10] = fmaf(x2.z, w, acc[10]); acc[11] = fmaf(x2.w, w, acc[11]);
        acc[12] = fmaf(x3.x, w, acc[12]); acc[13] = fmaf(x3.y, w, acc[13]);
        acc[14] = fmaf(x3.z, w, acc[14]); acc[15] = fmaf(x3.w, w, acc[15]);
    }
#pragma unroll
    for (int k = 0; k < 16; k++) {
        float v = fmaxf(acc[k], 0.f);
        h[(size_t)(n0 + k) * HID + j] = v;
        __half hv = __float2half(v);
        h16[(size_t)(n0 + k) * HID + j] = __builtin_bit_cast(unsigned short, hv);
    }
}

// ---------------- per-dst basis-weighted gather (fp16 h), 8-deep MLP, fp16 G output ----------------
__global__ void __launch_bounds__(256) k_mix2(
    const unsigned short* __restrict__ h16, const float* __restrict__ comp_l,
    const int* __restrict__ row_start, const int* __restrict__ edge_p,
    unsigned short* __restrict__ Gf, int c0, int nc) {
    __shared__ float cs[NUM_RELS * NUM_BASES];
    if (threadIdx.x < NUM_RELS * NUM_BASES) cs[threadIdx.x] = comp_l[threadIdx.x];
    __syncthreads();
    int wave = threadIdx.x >> 6, lane = threadIdx.x & 63;
    int n = c0 + blockIdx.x * 4 + wave;
    if (n >= c0 + nc) return;
    int e0 = row_start[n], e1 = row_start[n + 1];
    float2 acc[NUM_BASES];
#pragma unroll
    for (int b = 0; b < NUM_BASES; b++) acc[b] = make_float2(0.f, 0.f);
    int e = e0;
    for (; e + 8 <= e1; e += 8) {
        int p0 = edge_p[e],     p1 = edge_p[e + 1], p2 = edge_p[e + 2], p3 = edge_p[e + 3];
        int p4 = edge_p[e + 4], p5 = edge_p[e + 5], p6 = edge_p[e + 6], p7 = edge_p[e + 7];
        unsigned u0 = ((const unsigned*)(h16 + (size_t)(p0 >> 5) * HID))[lane];
        unsigned u1 = ((const unsigned*)(h16 + (size_t)(p1 >> 5) * HID))[lane];
        unsigned u2 = ((const unsigned*)(h16 + (size_t)(p2 >> 5) * HID))[lane];
        unsigned u3 = ((const unsigned*)(h16 + (size_t)(p3 >> 5) * HID))[lane];
        unsigned u4 = ((const unsigned*)(h16 + (size_t)(p4 >> 5) * HID))[lane];
        unsigned u5 = ((const unsigned*)(h16 + (size_t)(p5 >> 5) * HID))[lane];
        unsigned u6 = ((const unsigned*)(h16 + (size_t)(p6 >> 5) * HID))[lane];
        unsigned u7 = ((const unsigned*)(h16 + (size_t)(p7 >> 5) * HID))[lane];
        const float* c0p = &cs[(p0 & 31) * NUM_BASES];
        const float* c1p = &cs[(p1 & 31) * NUM_BASES];
        const float* c2p = &cs[(p2 & 31) * NUM_BASES];
        const float* c3p = &cs[(p3 & 31) * NUM_BASES];
        const float* c4p = &cs[(p4 & 31) * NUM_BASES];
        const float* c5p = &cs[(p5 & 31) * NUM_BASES];
        const float* c6p = &cs[(p6 & 31) * NUM_BASES];
        const float* c7p = &cs[(p7 & 31) * NUM_BASES];
        float2 v0 = __half22float2(__builtin_bit_cast(__half2, u0));
        float2 v1 = __half22float2(__builtin_bit_cast(__half2, u1));
        float2 v2 = __half22float2(__builtin_bit_cast(__half2, u2));
        float2 v3 = __half22float2(__builtin_bit_cast(__half2, u3));
        float2 v4 = __half22float2(__builtin_bit_cast(__half2, u4));
        float2 v5 = __half22float2(__builtin_bit_cast(__half2, u5));
        float2 v6 = __half22float2(__builtin_bit_cast(__half2, u6));
        float2 v7 = __half22float2(__builtin_bit_cast(__half2, u7));
#pragma unroll
        for (int b = 0; b < NUM_BASES; b++) {
            acc[b].x = fmaf(c0p[b], v0.x, acc[b].x);
            acc[b].y = fmaf(c0p[b], v0.y, acc[b].y);
            acc[b].x = fmaf(c1p[b], v1.x, acc[b].x);
            acc[b].y = fmaf(c1p[b], v1.y, acc[b].y);
            acc[b].x = fmaf(c2p[b], v2.x, acc[b].x);
            acc[b].y = fmaf(c2p[b], v2.y, acc[b].y);
            acc[b].x = fmaf(c3p[b], v3.x, acc[b].x);
            acc[b].y = fmaf(c3p[b], v3.y, acc[b].y);
            acc[b].x = fmaf(c4p[b], v4.x, acc[b].x);
            acc[b].y = fmaf(c4p[b], v4.y, acc[b].y);
            acc[b].x = fmaf(c5p[b], v5.x, acc[b].x);
            acc[b].y = fmaf(c5p[b], v5.y, acc[b].y);
            acc[b].x = fmaf(c6p[b], v6.x, acc[b].x);
            acc[b].y = fmaf(c6p[b], v6.y, acc[b].y);
            acc[b].x = fmaf(c7p[b], v7.x, acc[b].x);
            acc[b].y = fmaf(c7p[b], v7.y, acc[b].y);
        }
    }
    for (; e < e1; e++) {
        int se = edge_p[e];
        const float* c = &cs[(se & 31) * NUM_BASES];
        unsigned u = ((const unsigned*)(h16 + (size_t)(se >> 5) * HID))[lane];
        float2 v = __half22float2(__builtin_bit_cast(__half2, u));
#pragma unroll
        for (int b = 0; b < NUM_BASES; b++) {
            acc[b].x = fmaf(c[b], v.x, acc[b].x);
            acc[b].y = fmaf(c[b], v.y, acc[b].y);
        }
    }
    size_t base = (size_t)(n - c0) * 1024 + 2 * lane;
#pragma unroll
    for (int b = 0; b < NUM_BASES; b++) {
        __half2 g2 = __floats2half2_rn(acc[b].x, acc[b].y);
        *(unsigned*)&Gf[base + b * 128] = __builtin_bit_cast(unsigned, g2);
    }
}

// ---------------- B fragment table: f16 (hi only) of [Vl ; Wl], MFMA fragment order ----------------
__global__ void k_bfrag(const float* __restrict__ V, const float* __restrict__ W_loop,
                        unsigned short* __restrict__ Bf) {
    int idx = blockIdx.x * 256 + threadIdx.x;
    if (idx >= NUM_LAYERS * 36 * 8 * 64) return;
    int lane = idx & 63;
    int t = (idx >> 6) & 7;
    int s = (idx >> 9) % 36;
    int l = (idx >> 9) / 36;
    int col = t * 16 + (lane & 15);
    int kbase = s * 32 + (lane >> 4) * 8;
    unsigned short* o = Bf + (size_t)idx * 8;
#pragma unroll
    for (int j = 0; j < 8; j++) {
        int k = kbase + j;
        float f = (k < 1024) ? V[((size_t)l * 1024 + k) * HID + col]
                             : W_loop[((size_t)l * HID + (k - 1024)) * HID + col];
        __half hh = __float2half(f);
        o[j] = __builtin_bit_cast(unsigned short, hh);
    }
}

// ---------------- f16 MFMA GEMM (BM=64, BK=128, single-B) ----------------
__global__ void __launch_bounds__(256) k_gemm9(
    const unsigned short* __restrict__ Gf, const unsigned short* __restrict__ h16,
    const unsigned short* __restrict__ Bf, const float* __restrict__ bl,
    float* __restrict__ out, unsigned short* __restrict__ out16, int c0, int nc) {
    __shared__ unsigned short smem[2][16][512];  // [buf][frag][1KB] = 32KB
    int lane = threadIdx.x & 63;
    int w = threadIdx.x >> 6;
    int rit = lane & 15, kg = lane >> 4;
    int r0 = blockIdx.x * 64;
    int sr0 = r0 + 0 * 16 + rit; if (sr0 >= nc) sr0 = nc - 1;
    int sr1 = r0 + 1 * 16 + rit; if (sr1 >= nc) sr1 = nc - 1;
    int sr2 = r0 + 2 * 16 + rit; if (sr2 >= nc) sr2 = nc - 1;
    int sr3 = r0 + 3 * 16 + rit; if (sr3 >= nc) sr3 = nc - 1;
    int koff = w * 32 + kg * 8;
    const unsigned short* gs0 = Gf + (size_t)sr0 * 1024 + koff;
    const unsigned short* gs1 = Gf + (size_t)sr1 * 1024 + koff;
    const unsigned short* gs2 = Gf + (size_t)sr2 * 1024 + koff;
    const unsigned short* gs3 = Gf + (size_t)sr3 * 1024 + koff;
    const f16x8* bb = (const f16x8*)Bf + (size_t)(2 * w) * 64 + lane;
    f32x4 acc[4][2] = {};

#define STAGE(BUF, STEP) {                                        \
        gld_lds16(&smem[BUF][w * 4 + 0][0], gs0 + (STEP) * 128);  \
        gld_lds16(&smem[BUF][w * 4 + 1][0], gs1 + (STEP) * 128);  \
        gld_lds16(&smem[BUF][w * 4 + 2][0], gs2 + (STEP) * 128);  \
        gld_lds16(&smem[BUF][w * 4 + 3][0], gs3 + (STEP) * 128); }
#define CSTEP(BUF, STEP) _Pragma("unroll")                                   \
    for (int s = 0; s < 4; s++) {                                            \
        const f16x8* bp = bb + (size_t)((STEP) * 4 + s) * 512;               \
        f16x8 bh0 = bp[0], bh1 = bp[64];                                     \
        _Pragma("unroll")                                                    \
        for (int i = 0; i < 4; i++) {                                        \
            f16x8 a = *(const f16x8*)&smem[BUF][s * 4 + i][lane * 8];        \
            acc[i][0] = __builtin_amdgcn_mfma_f32_16x16x32_f16(a, bh0, acc[i][0], 0, 0, 0); \
            acc[i][1] = __builtin_amdgcn_mfma_f32_16x16x32_f16(a, bh1, acc[i][1], 0, 0, 0); \
        }                                                                    \
    }

    STAGE(0, 0);
    for (int t = 0; t < 8; t++) {
        __syncthreads();
        if (t < 7) STAGE((t + 1) & 1, t + 1);
        CSTEP(t & 1, t);
    }
    {
        const unsigned short* hp0 = h16 + (size_t)(c0 + sr0) * HID + kg * 8;
        const unsigned short* hp1 = h16 + (size_t)(c0 + sr1) * HID + kg * 8;
        const unsigned short* hp2 = h16 + (size_t)(c0 + sr2) * HID + kg * 8;
        const unsigned short* hp3 = h16 + (size_t)(c0 + sr3) * HID + kg * 8;
#pragma unroll
        for (int s = 32; s < 36; s++) {
            int o = (s - 32) * 32;
            f16x8 a0 = *(const f16x8*)(hp0 + o);
            f16x8 a1 = *(const f16x8*)(hp1 + o);
            f16x8 a2 = *(const f16x8*)(hp2 + o);
            f16x8 a3 = *(const f16x8*)(hp3 + o);
            const f16x8* bp = bb + (size_t)s * 512;
            f16x8 bh0 = bp[0], bh1 = bp[64];
            acc[0][0] = __builtin_amdgcn_mfma_f32_16x16x32_f16(a0, bh0, acc[0][0], 0, 0, 0);
            acc[0][1] = __builtin_amdgcn_mfma_f32_16x16x32_f16(a0, bh1, acc[0][1], 0, 0, 0);
            acc[1][0] = __builtin_amdgcn_mfma_f32_16x16x32_f16(a1, bh0, acc[1][0], 0, 0, 0);
            acc[1][1] = __builtin_amdgcn_mfma_f32_16x16x32_f16(a1, bh1, acc[1][1], 0, 0, 0);
            acc[2][0] = __builtin_amdgcn_mfma_f32_16x16x32_f16(a2, bh0, acc[2][0], 0, 0, 0);
            acc[2][1] = __builtin_amdgcn_mfma_f32_16x16x32_f16(a2, bh1, acc[2][1], 0, 0, 0);
            acc[3][0] = __builtin_amdgcn_mfma_f32_16x16x32_f16(a3, bh0, acc[3][0], 0, 0, 0);
            acc[3][1] = __builtin_amdgcn_mfma_f32_16x16x32_f16(a3, bh1, acc[3][1], 0, 0, 0);
        }
    }
#undef STAGE
#undef CSTEP
    int col0 = 2 * w * 16 + rit;
    float b0 = bl[col0], b1 = bl[col0 + 16];
#pragma unroll
    for (int i = 0; i < 4; i++) {
        int rq = r0 + i * 16 + kg * 4;
#pragma unroll
        for (int q = 0; q < 4; q++) {
            int row = rq + q;
            if (row < nc) {
                float v0 = fmaxf(acc[i][0][q] + b0, 0.f);
                float v1 = fmaxf(acc[i][1][q] + b1, 0.f);
                size_t o = (size_t)(c0 + row) * HID;
                out[o + col0] = v0; out[o + col0 + 16] = v1;
                out16[o + col0] = __builtin_bit_cast(unsigned short, __float2half(v0));
                out16[o + col0 + 16] = __builtin_bit_cast(unsigned short, __float2half(v1));
            }
        }
    }
}

// ---------------- attention scalar score per node (16 nodes/block) ----------------
__global__ void __launch_bounds__(128) k_score(
    const float* __restrict__ h, const float* __restrict__ er,
    const float* __restrict__ Wa, const float* __restrict__ ba,
    const float* __restrict__ wsc, const float* __restrict__ bsc,
    float* __restrict__ a) {
    int n0 = blockIdx.x * 16;
    int j = threadIdx.x;
    int u = j >> 3, q = j & 7;
    __shared__ float xT[160][16];
    {
        const float4* h4 = (const float4*)(h + (size_t)(n0 + u) * HID);
#pragma unroll
        for (int k = 0; k < 4; k++) {
            float4 v = h4[q + 8 * k];
            xT[32 * k + 4 * q + 0][u] = v.x; xT[32 * k + 4 * q + 1][u] = v.y;
            xT[32 * k + 4 * q + 2][u] = v.z; xT[32 * k + 4 * q + 3][u] = v.w;
        }
        float4 e4 = ((const float4*)(er + (size_t)(n0 + u) * REL_DIM))[q];
        xT[128 + 4 * q + 0][u] = e4.x; xT[128 + 4 * q + 1][u] = e4.y;
        xT[128 + 4 * q + 2][u] = e4.z; xT[128 + 4 * q + 3][u] = e4.w;
    }
    __syncthreads();
    float bj = ba[j];
    float acc[16];
#pragma unroll
    for (int k = 0; k < 16; k++) acc[k] = bj;
    for (int d = 0; d < 160; d++) {
        float w = Wa[d * HID + j];
        float4 x0 = *(const float4*)&xT[d][0];
        float4 x1 = *(const float4*)&xT[d][4];
        float4 x2 = *(const float4*)&xT[d][8];
        float4 x3 = *(const float4*)&xT[d][12];
        acc[0]  = fmaf(x0.x, w, acc[0]);  acc[1]  = fmaf(x0.y, w, acc[1]);
        acc[2]  = fmaf(x0.z, w, acc[2]);  acc[3]  = fmaf(x0.w, w, acc[3]);
        acc[4]  = fmaf(x1.x, w, acc[4]);  acc[5]  = fmaf(x1.y, w, acc[5]);
        acc[6]  = fmaf(x1.z, w, acc[6]);  acc[7]  = fmaf(x1.w, w, acc[7]);
        acc[8]  = fmaf(x2.x, w, acc[8]);  acc[9]  = fmaf(x2.y, w, acc[9]);
        acc[10] = fmaf(x2.z, w, acc[10]); acc[11] = fmaf(x2.w, w, acc[11]);
        acc[12] = fmaf(x3.x, w, acc[12]); acc[13] = fmaf(x3.y, w, acc[13]);
        acc[14] = fmaf(x3.z, w, acc[14]); acc[15] = fmaf(x3.w, w, acc[15]);
    }
    __shared__ float red[16][128];
    float wj = wsc[j];
#pragma unroll
    for (int k = 0; k < 16; k++) red[k][j] = tanhf(acc[k]) * wj;
    __syncthreads();
    for (int s = 64; s > 0; s >>= 1) {
        if (j < s) {
#pragma unroll
            for (int k = 0; k < 16; k++) red[k][j] += red[k][j + s];
        }
        __syncthreads();
    }
    if (j < 16) a[n0 + j] = red[j][0] + bsc[0];
}

// ---------------- graph boundaries (graph_id is sorted) ----------------
__global__ void k_starts(const int* __restrict__ gid, int* __restrict__ starts) {
    int g = threadIdx.x;  // 0..255
    int lo = 0, hi = N_NODES;
    while (lo < hi) {
        int mid = (lo + hi) >> 1;
        if (gid[mid] < g) lo = mid + 1; else hi = mid;
    }
    starts[g] = lo;
    if (g == 0) starts[NUM_GRAPHS] = N_NODES;
}

// ---------------- segment softmax pooling + final dot ----------------
__global__ void __launch_bounds__(128) k_pool(
    const float* __restrict__ h, const float* __restrict__ a,
    const int* __restrict__ starts, const float* __restrict__ wout,
    const float* __restrict__ bout, float* __restrict__ out) {
    int g = blockIdx.x, j = threadIdx.x;
    int s0 = starts[g], s1 = starts[g + 1];
    __shared__ float red[128];
    __shared__ float exb[128];
    if (s1 <= s0) { if (j == 0) out[g] = bout[0]; return; }
    float m = -3.4e38f;
    for (int i = s0 + j; i < s1; i += 128) m = fmaxf(m, a[i]);
    red[j] = m; __syncthreads();
    for (int s = 64; s > 0; s >>= 1) {
        if (j < s) red[j] = fmaxf(red[j], red[j + s]);
        __syncthreads();
    }
    m = red[0]; __syncthreads();
    float zj = 0.f, ss = 0.f;
    for (int base = s0; base < s1; base += 128) {
        int cnt = min(128, s1 - base);
        float ev = 0.f;
        if (j < cnt) ev = expf(a[base + j] - m);
        exb[j] = ev;
        ss += ev;
        __syncthreads();
        for (int k = 0; k < cnt; k++)
            zj = fmaf(exb[k], h[(size_t)(base + k) * HID + j], zj);
        __syncthreads();
    }
    red[j] = ss; __syncthreads();
    for (int s = 64; s > 0; s >>= 1) {
        if (j < s) red[j] += red[j + s];
        __syncthreads();
    }
    ss = red[0]; __syncthreads();
    red[j] = (zj / ss) * wout[j]; __syncthreads();
    for (int s = 64; s > 0; s >>= 1) {
        if (j < s) red[j] += red[j + s];
        __syncthreads();
    }
    if (j == 0) out[g] = red[0] + bout[0];
}

extern "C" void kernel_launch(void* const* d_in, const int* in_sizes, int n_in,
                              void* d_out, int out_size, void* d_ws, size_t ws_size,
                              hipStream_t stream) {
    const float* feat    = (const float*)d_in[0];
    const int*   qrel    = (const int*)d_in[1];
    const int*   src     = (const int*)d_in[2];
    const int*   dst     = (const int*)d_in[3];
    const int*   ety     = (const int*)d_in[4];
    const int*   gid     = (const int*)d_in[5];
    const float* rel_emb = (const float*)d_in[6];
    const float* W_in    = (const float*)d_in[7];
    const float* b_in    = (const float*)d_in[8];
    const float* V       = (const float*)d_in[9];
    const float* comp    = (const float*)d_in[10];
    const float* W_loop  = (const float*)d_in[11];
    const float* b_loop  = (const float*)d_in[12];
    const float* W_attn  = (const float*)d_in[13];
    const float* b_attn  = (const float*)d_in[14];
    const float* w_sc    = (const float*)d_in[15];
    const float* b_sc    = (const float*)d_in[16];
    const float* w_out   = (const float*)d_in[17];
    const float* b_out   = (const float*)d_in[18];
    float* out = (float*)d_out;

    float* ws = (float*)d_ws;
    float* h0 = ws;                                       // 6.4M floats
    float* h1 = h0 + (size_t)N_NODES * HID;               // 6.4M
    unsigned short* h16a = (unsigned short*)(h1 + (size_t)N_NODES * HID);  // 6.4M ushort
    unsigned short* h16b = h16a + (size_t)N_NODES * HID;                   // 6.4M ushort
    float* er = (float*)(h16b + (size_t)N_NODES * HID);   // 1.6M
    float* af = er + (size_t)N_NODES * REL_DIM;           // 50000
    int* starts    = (int*)(af + N_NODES);                // 260
    int* row_start = starts + 260;                        // 50004
    int* off       = row_start + 50004;                   // 100352
    int* bsum      = off + OFFN;                          // 392
    int* boff      = bsum + SC2_BLKS;                     // 392
    int* tmp_e     = boff + SC2_BLKS;                     // 800000
    int* edge_p    = tmp_e + 800000;                      // 800000
    unsigned short* Bf = (unsigned short*)(edge_p + 800000);  // 2*36*8*64*8 ushort (hi only)
    const size_t BF_USHORT = (size_t)NUM_LAYERS * 36 * 8 * 64 * 8;
    unsigned short* Gf = Bf + BF_USHORT;

    size_t used_floats = (size_t)((float*)Gf - ws);
    size_t total_floats = ws_size / sizeof(float);
    size_t avail = (total_floats > used_floats) ? (total_floats - used_floats) : 0;
    long long NC = (long long)(avail / 512);   // 1024 fp16 per row = 512 floats
    NC = (NC / 64) * 64;
    if (NC > 50048) NC = 50048;
    if (NC < 64) NC = 64;

    // --- preprocessing: bucketed counting sort -> edge_p + row_start ---
    k_bhist<<<PBLK, 256, 0, stream>>>(dst, off);
    k_scan2_a<<<SC2_BLKS, 256, 0, stream>>>(off, bsum);
    k_scan2_b<<<1, 512, 0, stream>>>(bsum, boff);
    k_scan2_c<<<SC2_BLKS, 256, 0, stream>>>(off, boff);
    k_bscatter<<<PBLK, 256, 0, stream>>>(src, dst, ety, off, tmp_e);
    k_bsort<<<NBUCK, 256, 0, stream>>>(off, tmp_e, edge_p, row_start);
    k_bfrag<<<(NUM_LAYERS * 36 * 8 * 64 + 255) / 256, 256, 0, stream>>>(V, W_loop, Bf);
    k_input<<<N_NODES / 16, 128, 0, stream>>>(feat, qrel, rel_emb, W_in, b_in, h0, h16a, er);

    float* hcur = h0;
    float* hnext = h1;
    unsigned short* h16cur = h16a;
    unsigned short* h16next = h16b;
    for (int l = 0; l < NUM_LAYERS; l++) {
        const float* comp_l = comp + (size_t)l * NUM_RELS * NUM_BASES;
        const unsigned short* Bfl = Bf + (size_t)l * 36 * 8 * 64 * 8;
        const float* bl = b_loop + (size_t)l * HID;
        for (int c0 = 0; c0 < N_NODES; c0 += (int)NC) {
            int nc = (int)((N_NODES - c0 < NC) ? (N_NODES - c0) : NC);
            k_mix2<<<(nc + 3) / 4, 256, 0, stream>>>(h16cur, comp_l, row_start, edge_p,
                                                     Gf, c0, nc);
            k_gemm9<<<(nc + 63) / 64, 256, 0, stream>>>(Gf, h16cur, Bfl, bl,
                                                        hnext, h16next, c0, nc);
        }
        float* tmp = hcur; hcur = hnext; hnext = tmp;
        unsigned short* tmp16 = h16cur; h16cur = h16next; h16next = tmp16;
    }

    k_score<<<N_NODES / 16, 128, 0, stream>>>(hcur, er, W_attn, b_attn, w_sc, b_sc, af);
    k_starts<<<1, 256, 0, stream>>>(gid, starts);
    k_pool<<<NUM_GRAPHS, 128, 0, stream>>>(hcur, af, starts, w_out, b_out, out);
}